// Round 1
// 414.385 us; speedup vs baseline: 1.1304x; 1.1304x over previous
//
#include <hip/hip_runtime.h>
#include <hip/hip_bf16.h>

#define N_NODES   50000
#define N_EDGES   800000
#define NUM_GRAPHS 256
#define IN_DIM    128
#define HD        64
#define EPS       1e-5f
#define SCAN_NB   196      // ceil(50000/256)
#define NB_HEAD   64       // head kernel grid (must be <= CU count for co-residency)

typedef __hip_bfloat16 bf16;

// ---------------- diagnostics ----------------
__global__ void k_diag(float* __restrict__ out, int n, float v) {
    int t = blockIdx.x * 256 + threadIdx.x;
    if (t < n) out[t] = v;
}

// ---------------- CSR build (+ graph bounds for pooling) ----------------
__global__ void k_count(const int* __restrict__ dst, const int* __restrict__ batch,
                        int* __restrict__ cnti, int* __restrict__ pos,
                        int* __restrict__ gb) {
    int e = blockIdx.x * 256 + threadIdx.x;
    if (e < N_EDGES) pos[e] = atomicAdd(&cnti[dst[e]], 1);
    // graph bounds: gb[g] = first node index with batch >= g (batch is sorted)
    if (e < N_NODES) {
        int bg = batch[e];
        int bnext = (e + 1 < N_NODES) ? batch[e + 1] : NUM_GRAPHS;
        if (e == 0) {
            for (int g = 0; g <= bg; ++g) gb[g] = 0;
        }
        for (int g = bg + 1; g <= bnext; ++g) gb[g] = e + 1;
    }
}

__global__ void k_scan1(const int* __restrict__ cnti, int* __restrict__ off,
                        int* __restrict__ bsum) {
    __shared__ int wsum[4];
    int idx = blockIdx.x * 256 + threadIdx.x;
    int lane = threadIdx.x & 63, wid = threadIdx.x >> 6;
    int v = (idx < N_NODES) ? cnti[idx] : 0;
    int s = v;
    #pragma unroll
    for (int o = 1; o < 64; o <<= 1) {
        int u = __shfl_up(s, o);
        if (lane >= o) s += u;
    }
    if (lane == 63) wsum[wid] = s;
    __syncthreads();
    int wbase = 0;
    #pragma unroll
    for (int w = 0; w < 4; w++) wbase += (w < wid) ? wsum[w] : 0;
    if (idx < N_NODES) off[idx] = wbase + s - v;
    if (threadIdx.x == 255) bsum[blockIdx.x] = wbase + s;
}

__global__ void k_scan3(int* __restrict__ off, const int* __restrict__ bsum) {
    __shared__ int wsum[4];
    __shared__ int spre;
    int lane = threadIdx.x & 63, wid = threadIdx.x >> 6;
    int v = (threadIdx.x < blockIdx.x) ? bsum[threadIdx.x] : 0;
    #pragma unroll
    for (int o = 32; o > 0; o >>= 1) v += __shfl_down(v, o);
    if (lane == 0) wsum[wid] = v;
    __syncthreads();
    if (threadIdx.x == 0) spre = wsum[0] + wsum[1] + wsum[2] + wsum[3];
    __syncthreads();
    int pre = spre;
    int idx = blockIdx.x * 256 + threadIdx.x;
    if (idx < N_NODES) off[idx] += pre;
    else if (idx == N_NODES) off[N_NODES] = N_EDGES;
}

__global__ void k_fill(const int* __restrict__ src, const int* __restrict__ dst,
                       const int* __restrict__ off, const int* __restrict__ pos,
                       int* __restrict__ nbr) {
    int e = blockIdx.x * 256 + threadIdx.x;
    if (e >= N_EDGES) return;
    int d = dst[e];
    nbr[off[d] + pos[e]] = src[e];
}

// ---- fused transform, LDS-staged X tile: B(bf16) = X@Wl ; C = X@Wr + bl ----
template <int K>
__global__ __launch_bounds__(256) void k_xform3(
        const float* __restrict__ X, const float* __restrict__ Wl,
        const float* __restrict__ Wr, const float* __restrict__ bl,
        bf16* __restrict__ B, float* __restrict__ C) {
    __shared__ float tile[32 * K];
    const int NPW = 8;
    int nodes0 = blockIdx.x * 32;
    {
        const int total4 = 32 * K / 4;
        int nmax4 = (N_NODES - nodes0) * K / 4;
        const float4* Xg = (const float4*)(X + (long)nodes0 * K);
        float4* tg = (float4*)tile;
        for (int idx = threadIdx.x; idx < total4; idx += 256) {
            float4 v = make_float4(0.f, 0.f, 0.f, 0.f);
            if (idx < nmax4) v = Xg[idx];
            tg[idx] = v;
        }
    }
    __syncthreads();
    int wave = threadIdx.x >> 6, j = threadIdx.x & 63;
    long base = (long)nodes0 + wave * NPW;
    if (base >= N_NODES) return;
    float accB[NPW], accC[NPW];
    #pragma unroll
    for (int n = 0; n < NPW; n++) { accB[n] = 0.f; accC[n] = 0.f; }
    const float* Xs = tile + (wave * NPW) * K;
    for (int kc = 0; kc < K; kc += 4) {
        float wl0 = Wl[(kc + 0) * HD + j], wr0 = Wr[(kc + 0) * HD + j];
        float wl1 = Wl[(kc + 1) * HD + j], wr1 = Wr[(kc + 1) * HD + j];
        float wl2 = Wl[(kc + 2) * HD + j], wr2 = Wr[(kc + 2) * HD + j];
        float wl3 = Wl[(kc + 3) * HD + j], wr3 = Wr[(kc + 3) * HD + j];
        #pragma unroll
        for (int n = 0; n < NPW; n++) {
            float4 xv = *(const float4*)(Xs + n * K + kc);
            accB[n] = fmaf(xv.x, wl0, accB[n]);
            accC[n] = fmaf(xv.x, wr0, accC[n]);
            accB[n] = fmaf(xv.y, wl1, accB[n]);
            accC[n] = fmaf(xv.y, wr1, accC[n]);
            accB[n] = fmaf(xv.z, wl2, accB[n]);
            accC[n] = fmaf(xv.z, wr2, accC[n]);
            accB[n] = fmaf(xv.w, wl3, accB[n]);
            accC[n] = fmaf(xv.w, wr3, accC[n]);
        }
    }
    float bb = bl[j];
    int nact = (int)min((long)NPW, (long)N_NODES - base);
    for (int n = 0; n < nact; n++) {
        long i = base + n;
        B[i * HD + j] = __float2bfloat16(accB[n]);
        C[i * HD + j] = accC[n] + bb;
    }
}

__device__ __forceinline__ float bflo(unsigned u) { return __uint_as_float(u << 16); }
__device__ __forceinline__ float bfhi(unsigned u) { return __uint_as_float(u & 0xffff0000u); }

// ---- CSR gather, pairwise (2 neighbor rows per wave-load) ----
__global__ void k_gather(const int* __restrict__ off, const int* __restrict__ nbr,
                         const bf16* __restrict__ Bm, float* __restrict__ C) {
    int t = blockIdx.x * 256 + threadIdx.x;
    int i = t >> 6, lane = t & 63;
    if (i >= N_NODES) return;
    int half = lane >> 5, c = lane & 31;
    const unsigned* B2 = (const unsigned*)Bm;
    int beg = off[i], end = off[i + 1];
    float e0 = 0.f, e1 = 0.f, e2 = 0.f, e3 = 0.f;
    float e4 = 0.f, e5 = 0.f, e6 = 0.f, e7 = 0.f;
    float o0 = 0.f, o1 = 0.f, o2 = 0.f, o3 = 0.f;
    float o4 = 0.f, o5 = 0.f, o6 = 0.f, o7 = 0.f;
    for (int base = beg; base < end; base += 64) {
        int idx = base + lane;
        int nv = (idx < end) ? nbr[idx] : 0;
        int m = min(64, end - base);
        int tt = 0;
        for (; tt + 16 <= m; tt += 16) {
            int n0 = __shfl(nv, tt + 0 + half);
            int n1 = __shfl(nv, tt + 2 + half);
            int n2 = __shfl(nv, tt + 4 + half);
            int n3 = __shfl(nv, tt + 6 + half);
            int n4 = __shfl(nv, tt + 8 + half);
            int n5 = __shfl(nv, tt + 10 + half);
            int n6 = __shfl(nv, tt + 12 + half);
            int n7 = __shfl(nv, tt + 14 + half);
            unsigned u0 = B2[(long)n0 * 32 + c];
            unsigned u1 = B2[(long)n1 * 32 + c];
            unsigned u2 = B2[(long)n2 * 32 + c];
            unsigned u3 = B2[(long)n3 * 32 + c];
            unsigned u4 = B2[(long)n4 * 32 + c];
            unsigned u5 = B2[(long)n5 * 32 + c];
            unsigned u6 = B2[(long)n6 * 32 + c];
            unsigned u7 = B2[(long)n7 * 32 + c];
            e0 += bflo(u0); o0 += bfhi(u0);
            e1 += bflo(u1); o1 += bfhi(u1);
            e2 += bflo(u2); o2 += bfhi(u2);
            e3 += bflo(u3); o3 += bfhi(u3);
            e4 += bflo(u4); o4 += bfhi(u4);
            e5 += bflo(u5); o5 += bfhi(u5);
            e6 += bflo(u6); o6 += bfhi(u6);
            e7 += bflo(u7); o7 += bfhi(u7);
        }
        for (; tt + 2 <= m; tt += 2) {
            int n0 = __shfl(nv, tt + half);
            unsigned u0 = B2[(long)n0 * 32 + c];
            e0 += bflo(u0); o0 += bfhi(u0);
        }
        if (tt < m) {
            int n0 = __shfl(nv, tt);
            if (half == 0) {
                unsigned u0 = B2[(long)n0 * 32 + c];
                e0 += bflo(u0); o0 += bfhi(u0);
            }
        }
    }
    float es = ((e0 + e1) + (e2 + e3)) + ((e4 + e5) + (e6 + e7));
    float os = ((o0 + o1) + (o2 + o3)) + ((o4 + o5) + (o6 + o7));
    es += __shfl(es, lane ^ 32);
    os += __shfl(os, lane ^ 32);
    if (half == 0) {
        int deg = end - beg;
        float inv = 1.0f / (float)max(deg, 1);
        float2* Cp = (float2*)(C + (long)i * HD + 2 * c);
        float2 cur = *Cp;
        cur.x += es * inv;
        cur.y += os * inv;
        *Cp = cur;
    }
}

// ---------------- fused head: pool + 3x(lin+BN+tanh) + lin4 ----------------
// Grid barrier: device-scope atomic counter, monotonically increasing rounds.
// NB_HEAD = 64 blocks <= 256 CUs -> all blocks co-resident; bar zeroed by the
// launcher memset every replay.
__device__ __forceinline__ void gbar(int* bar, int round) {
    __syncthreads();
    if (threadIdx.x == 0) {
        __threadfence();
        __hip_atomic_fetch_add(bar, 1, __ATOMIC_RELEASE, __HIP_MEMORY_SCOPE_AGENT);
        int target = round * NB_HEAD;
        while (__hip_atomic_load(bar, __ATOMIC_ACQUIRE, __HIP_MEMORY_SCOPE_AGENT) < target) {}
        __threadfence();
    }
    __syncthreads();
}

// One lin+BN+tanh stage. Block owns C complete output columns -> BN stats are
// block-local (reduction over all 256 rows happens inside the block).
// 256 threads: jj = t % C (column), rg = t / C (rowgroup); C rows per thread.
template <int N, int K, int C>
__device__ __forceinline__ void lin_stage(
        const float* __restrict__ A, const float* __restrict__ W,
        const float* __restrict__ bia, const float* __restrict__ gam,
        const float* __restrict__ bet, float* __restrict__ out,
        float* s_sum, float* s_sq, float* s_m, float* s_sc) {
    const int NRG = 256 / C;
    int t = threadIdx.x;
    int jj = t & (C - 1);
    int rg = t / C;
    int j = blockIdx.x * C + jj;
    float vals[C];
    float bj = bia[j];
    #pragma unroll
    for (int i = 0; i < C; i++) vals[i] = bj;
    #pragma unroll 8
    for (int k = 0; k < K; k += 4) {
        float w0 = W[(k + 0) * N + j];
        float w1 = W[(k + 1) * N + j];
        float w2 = W[(k + 2) * N + j];
        float w3 = W[(k + 3) * N + j];
        #pragma unroll
        for (int i = 0; i < C; i++) {
            int r = rg + NRG * i;
            float4 a = *(const float4*)(A + r * K + k);
            vals[i] = fmaf(a.x, w0, vals[i]);
            vals[i] = fmaf(a.y, w1, vals[i]);
            vals[i] = fmaf(a.z, w2, vals[i]);
            vals[i] = fmaf(a.w, w3, vals[i]);
        }
    }
    float sum = 0.f, sq = 0.f;
    #pragma unroll
    for (int i = 0; i < C; i++) { sum += vals[i]; sq += vals[i] * vals[i]; }
    int lane = t & 63, wid = t >> 6;
    // butterfly across rowgroups within the wave (lanes with equal jj)
    #pragma unroll
    for (int o = C; o < 64; o <<= 1) {
        sum += __shfl_xor(sum, o);
        sq  += __shfl_xor(sq, o);
    }
    if (lane < C) { s_sum[wid * C + lane] = sum; s_sq[wid * C + lane] = sq; }
    __syncthreads();
    if (t < C) {
        float S = s_sum[t] + s_sum[C + t] + s_sum[2 * C + t] + s_sum[3 * C + t];
        float Q = s_sq[t]  + s_sq[C + t]  + s_sq[2 * C + t]  + s_sq[3 * C + t];
        float mean = S * (1.0f / NUM_GRAPHS);
        float var = Q * (1.0f / NUM_GRAPHS) - mean * mean;
        s_m[t] = mean;
        s_sc[t] = rsqrtf(fmaxf(var, 0.f) + EPS) * gam[blockIdx.x * C + t];
    }
    __syncthreads();
    float mean = s_m[jj], sc = s_sc[jj], sh = bet[j];
    #pragma unroll
    for (int i = 0; i < C; i++) {
        out[(rg + NRG * i) * N + j] = tanhf((vals[i] - mean) * sc + sh);
    }
}

__global__ __launch_bounds__(256) void k_head(
        const int* __restrict__ gb, const float* __restrict__ h, int* bar,
        const float* __restrict__ l1w, const float* __restrict__ l1b,
        const float* __restrict__ g1, const float* __restrict__ be1,
        const float* __restrict__ l2w, const float* __restrict__ l2b,
        const float* __restrict__ g2, const float* __restrict__ be2,
        const float* __restrict__ l3w, const float* __restrict__ l3b,
        const float* __restrict__ g3, const float* __restrict__ be3,
        const float* __restrict__ w4, const float* __restrict__ b4,
        float* __restrict__ cb, float* __restrict__ m1,
        float* __restrict__ m2, float* __restrict__ m3,
        float* __restrict__ out) {
    __shared__ float s_sum[16], s_sq[16], s_m[4], s_sc[4];
    int t = threadIdx.x, lane = t & 63, wid = t >> 6;

    // stage 0: global mean pool — one wave per graph (64 blocks x 4 waves)
    {
        int g = blockIdx.x * 4 + wid;
        int beg = gb[g], end = gb[g + 1];
        float s0 = 0.f, s1 = 0.f, s2 = 0.f, s3 = 0.f;
        int n = beg;
        for (; n + 4 <= end; n += 4) {
            s0 += h[(long)(n + 0) * HD + lane];
            s1 += h[(long)(n + 1) * HD + lane];
            s2 += h[(long)(n + 2) * HD + lane];
            s3 += h[(long)(n + 3) * HD + lane];
        }
        for (; n < end; n++) s0 += h[(long)n * HD + lane];
        float tot = (s0 + s1) + (s2 + s3);
        cb[g * HD + lane] = tot / (float)max(end - beg, 1);
    }
    gbar(bar, 1);
    lin_stage<256, 64, 4>(cb, l1w, l1b, g1, be1, m1, s_sum, s_sq, s_m, s_sc);
    gbar(bar, 2);
    lin_stage<128, 256, 2>(m1, l2w, l2b, g2, be2, m2, s_sum, s_sq, s_m, s_sc);
    gbar(bar, 3);
    lin_stage<64, 128, 1>(m2, l3w, l3b, g3, be3, m3, s_sum, s_sq, s_m, s_sc);
    gbar(bar, 4);
    // lin4: 4 rows per block, 10 outputs per row
    if (t < 40) {
        int q = t / 10, jf = t % 10;
        int row = blockIdx.x * 4 + q;
        const float* rp = m3 + row * 64;
        float s = b4[jf];
        #pragma unroll
        for (int k = 0; k < 64; k++) s = fmaf(rp[k], w4[k * 10 + jf], s);
        out[row * 10 + jf] = s;
    }
}

extern "C" void kernel_launch(void* const* d_in, const int* in_sizes, int n_in,
                              void* d_out, int out_size, void* d_ws, size_t ws_size,
                              hipStream_t stream) {
    const float* x     = (const float*)d_in[0];
    const int*   ei    = (const int*) d_in[1];
    const int*   batch = (const int*) d_in[2];
    const float *W1l = (const float*)d_in[3],  *b1l = (const float*)d_in[4],  *W1r = (const float*)d_in[5];
    const float *W2l = (const float*)d_in[6],  *b2l = (const float*)d_in[7],  *W2r = (const float*)d_in[8];
    const float *W3l = (const float*)d_in[9],  *b3l = (const float*)d_in[10], *W3r = (const float*)d_in[11];
    const float *lin1_w = (const float*)d_in[12], *lin1_b = (const float*)d_in[13];
    const float *g1 = (const float*)d_in[14], *be1 = (const float*)d_in[15];
    const float *lin2_w = (const float*)d_in[16], *lin2_b = (const float*)d_in[17];
    const float *g2 = (const float*)d_in[18], *be2 = (const float*)d_in[19];
    const float *lin3_w = (const float*)d_in[20], *lin3_b = (const float*)d_in[21];
    const float *g3 = (const float*)d_in[22], *be3 = (const float*)d_in[23];
    const float *lin4_w = (const float*)d_in[24], *lin4_b = (const float*)d_in[25];

    const int* srcp = ei;
    const int* dstp = ei + N_EDGES;

    // ---- workspace layout ----
    const long NF = (long)N_NODES * HD;              // 3,200,000
    char* wsb  = (char*)d_ws;
    int*  cnti = (int*)wsb;                          // 50,048
    int*  bar  = cnti + 50048;                       // 8 (zeroed with cnti)
    int*  pos  = bar  + 8;                           // 800,000
    int*  off  = pos  + 800000;                      // 50,056
    int*  nbr  = off  + 50056;                       // 800,000
    int*  bsum = nbr  + 800000;                      // 256
    int*  gb   = bsum + 256;                         // 264 (257 used)
    bf16* B    = (bf16*)(gb + 264);                  // 3,200,000 bf16
    float* H1  = (float*)(B + NF);                   // 3,200,000
    float* H2  = H1  + NF;                           // 3,200,000
    float* cb  = H2  + NF;                           // 16,384
    float* m1  = cb  + NUM_GRAPHS * HD;              // 65,536
    float* m2  = m1  + NUM_GRAPHS * 256;             // 32,768
    float* m3  = m2  + NUM_GRAPHS * 128;             // 16,384
    float* endp= m3  + NUM_GRAPHS * 64;

    const size_t NEED = (size_t)((char*)endp - wsb);
    if (ws_size < NEED) {
        k_diag<<<(out_size + 255) / 256, 256, 0, stream>>>((float*)d_out, out_size,
                                                           (float)(ws_size >> 20));
        return;
    }

    const int TB = 256;
    const int gNE = (N_EDGES + TB - 1) / TB;
    const int gNF = (int)((NF + TB - 1) / TB);        // 12500
    const int gXB = (N_NODES + 31) / 32;              // 1563

    hipMemsetAsync(cnti, 0, (50048 + 8) * sizeof(int), stream);

    // ---- CSR build (+ graph bounds) ----
    k_count<<<gNE, TB, 0, stream>>>(dstp, batch, cnti, pos, gb);
    k_scan1<<<SCAN_NB, TB, 0, stream>>>(cnti, off, bsum);
    k_scan3<<<SCAN_NB, TB, 0, stream>>>(off, bsum);
    k_fill<<<gNE, TB, 0, stream>>>(srcp, dstp, off, pos, nbr);

    // ---- SAGE layers (bf16 messages, pairwise gather) ----
    k_xform3<IN_DIM><<<gXB, TB, 0, stream>>>(x, W1l, W1r, b1l, B, H1);
    k_gather<<<gNF, TB, 0, stream>>>(off, nbr, B, H1);
    k_xform3<HD><<<gXB, TB, 0, stream>>>(H1, W2l, W2r, b2l, B, H2);
    k_gather<<<gNF, TB, 0, stream>>>(off, nbr, B, H2);
    k_xform3<HD><<<gXB, TB, 0, stream>>>(H2, W3l, W3r, b3l, B, H1);
    k_gather<<<gNF, TB, 0, stream>>>(off, nbr, B, H1);

    // ---- fused head: pool + lin1/2/3 (+BN+tanh) + lin4, one dispatch ----
    k_head<<<NB_HEAD, TB, 0, stream>>>(gb, H1, bar,
                                       lin1_w, lin1_b, g1, be1,
                                       lin2_w, lin2_b, g2, be2,
                                       lin3_w, lin3_b, g3, be3,
                                       lin4_w, lin4_b,
                                       cb, m1, m2, m3, (float*)d_out);
}

// Round 2
// 401.150 us; speedup vs baseline: 1.1677x; 1.0330x over previous
//
#include <hip/hip_runtime.h>
#include <hip/hip_bf16.h>

#define N_NODES   50000
#define N_EDGES   800000
#define NUM_GRAPHS 256
#define IN_DIM    128
#define HD        64
#define EPS       1e-5f
#define SCAN_NB   196      // ceil(50000/256)
#define NB_HEAD   64       // head kernel grid (must be <= CU count for co-residency)

typedef __hip_bfloat16 bf16;

// ---------------- diagnostics ----------------
__global__ void k_diag(float* __restrict__ out, int n, float v) {
    int t = blockIdx.x * 256 + threadIdx.x;
    if (t < n) out[t] = v;
}

// ---------------- CSR build (+ graph bounds for pooling) ----------------
__global__ void k_count(const int* __restrict__ dst, const int* __restrict__ batch,
                        int* __restrict__ cnti, int* __restrict__ pos,
                        int* __restrict__ gb) {
    int e = blockIdx.x * 256 + threadIdx.x;
    if (e < N_EDGES) pos[e] = atomicAdd(&cnti[dst[e]], 1);
    // graph bounds: gb[g] = first node index with batch >= g (batch is sorted)
    if (e < N_NODES) {
        int bg = batch[e];
        int bnext = (e + 1 < N_NODES) ? batch[e + 1] : NUM_GRAPHS;
        if (e == 0) {
            for (int g = 0; g <= bg; ++g) gb[g] = 0;
        }
        for (int g = bg + 1; g <= bnext; ++g) gb[g] = e + 1;
    }
}

__global__ void k_scan1(const int* __restrict__ cnti, int* __restrict__ off,
                        int* __restrict__ bsum) {
    __shared__ int wsum[4];
    int idx = blockIdx.x * 256 + threadIdx.x;
    int lane = threadIdx.x & 63, wid = threadIdx.x >> 6;
    int v = (idx < N_NODES) ? cnti[idx] : 0;
    int s = v;
    #pragma unroll
    for (int o = 1; o < 64; o <<= 1) {
        int u = __shfl_up(s, o);
        if (lane >= o) s += u;
    }
    if (lane == 63) wsum[wid] = s;
    __syncthreads();
    int wbase = 0;
    #pragma unroll
    for (int w = 0; w < 4; w++) wbase += (w < wid) ? wsum[w] : 0;
    if (idx < N_NODES) off[idx] = wbase + s - v;
    if (threadIdx.x == 255) bsum[blockIdx.x] = wbase + s;
}

__global__ void k_scan3(int* __restrict__ off, const int* __restrict__ bsum,
                        const int* __restrict__ gb, float* __restrict__ invc) {
    __shared__ int wsum[4];
    __shared__ int spre;
    int lane = threadIdx.x & 63, wid = threadIdx.x >> 6;
    int v = (threadIdx.x < blockIdx.x) ? bsum[threadIdx.x] : 0;
    #pragma unroll
    for (int o = 32; o > 0; o >>= 1) v += __shfl_down(v, o);
    if (lane == 0) wsum[wid] = v;
    __syncthreads();
    if (threadIdx.x == 0) spre = wsum[0] + wsum[1] + wsum[2] + wsum[3];
    __syncthreads();
    int pre = spre;
    int idx = blockIdx.x * 256 + threadIdx.x;
    if (idx < N_NODES) off[idx] += pre;
    else if (idx == N_NODES) off[N_NODES] = N_EDGES;
    // per-graph 1/count for fused pooling (gb ready since k_count)
    if (blockIdx.x == 0 && threadIdx.x < NUM_GRAPHS) {
        int c0 = gb[threadIdx.x], c1 = gb[threadIdx.x + 1];
        invc[threadIdx.x] = 1.0f / (float)max(c1 - c0, 1);
    }
}

__global__ void k_fill(const int* __restrict__ src, const int* __restrict__ dst,
                       const int* __restrict__ off, const int* __restrict__ pos,
                       int* __restrict__ nbr) {
    int e = blockIdx.x * 256 + threadIdx.x;
    if (e >= N_EDGES) return;
    int d = dst[e];
    nbr[off[d] + pos[e]] = src[e];
}

// ---- fused transform, LDS-staged X tile: B(bf16) = X@Wl ; C = X@Wr + bl ----
template <int K>
__global__ __launch_bounds__(256) void k_xform3(
        const float* __restrict__ X, const float* __restrict__ Wl,
        const float* __restrict__ Wr, const float* __restrict__ bl,
        bf16* __restrict__ B, float* __restrict__ C) {
    __shared__ float tile[32 * K];
    const int NPW = 8;
    int nodes0 = blockIdx.x * 32;
    {
        const int total4 = 32 * K / 4;
        int nmax4 = (N_NODES - nodes0) * K / 4;
        const float4* Xg = (const float4*)(X + (long)nodes0 * K);
        float4* tg = (float4*)tile;
        for (int idx = threadIdx.x; idx < total4; idx += 256) {
            float4 v = make_float4(0.f, 0.f, 0.f, 0.f);
            if (idx < nmax4) v = Xg[idx];
            tg[idx] = v;
        }
    }
    __syncthreads();
    int wave = threadIdx.x >> 6, j = threadIdx.x & 63;
    long base = (long)nodes0 + wave * NPW;
    if (base >= N_NODES) return;
    float accB[NPW], accC[NPW];
    #pragma unroll
    for (int n = 0; n < NPW; n++) { accB[n] = 0.f; accC[n] = 0.f; }
    const float* Xs = tile + (wave * NPW) * K;
    for (int kc = 0; kc < K; kc += 4) {
        float wl0 = Wl[(kc + 0) * HD + j], wr0 = Wr[(kc + 0) * HD + j];
        float wl1 = Wl[(kc + 1) * HD + j], wr1 = Wr[(kc + 1) * HD + j];
        float wl2 = Wl[(kc + 2) * HD + j], wr2 = Wr[(kc + 2) * HD + j];
        float wl3 = Wl[(kc + 3) * HD + j], wr3 = Wr[(kc + 3) * HD + j];
        #pragma unroll
        for (int n = 0; n < NPW; n++) {
            float4 xv = *(const float4*)(Xs + n * K + kc);
            accB[n] = fmaf(xv.x, wl0, accB[n]);
            accC[n] = fmaf(xv.x, wr0, accC[n]);
            accB[n] = fmaf(xv.y, wl1, accB[n]);
            accC[n] = fmaf(xv.y, wr1, accC[n]);
            accB[n] = fmaf(xv.z, wl2, accB[n]);
            accC[n] = fmaf(xv.z, wr2, accC[n]);
            accB[n] = fmaf(xv.w, wl3, accB[n]);
            accC[n] = fmaf(xv.w, wr3, accC[n]);
        }
    }
    float bb = bl[j];
    int nact = (int)min((long)NPW, (long)N_NODES - base);
    for (int n = 0; n < nact; n++) {
        long i = base + n;
        B[i * HD + j] = __float2bfloat16(accB[n]);
        C[i * HD + j] = accC[n] + bb;
    }
}

__device__ __forceinline__ float bflo(unsigned u) { return __uint_as_float(u << 16); }
__device__ __forceinline__ float bfhi(unsigned u) { return __uint_as_float(u & 0xffff0000u); }

// ---- CSR gather, pairwise (2 neighbor rows per wave-load) ----
// LAST=true: instead of writing C, fuse the global mean pool: accumulate
// (C_row + mean_aggr) * invc[batch[i]] into cb via device-scope atomics.
// Grid covers exactly 50000 nodes (12500 blocks x 4 nodes) -> no early return.
template <bool LAST>
__global__ void k_gather(const int* __restrict__ off, const int* __restrict__ nbr,
                         const bf16* __restrict__ Bm, float* __restrict__ C,
                         const int* __restrict__ batch, const float* __restrict__ invc,
                         float* __restrict__ cb) {
    int t = blockIdx.x * 256 + threadIdx.x;
    int i = t >> 6, lane = t & 63;
    if (!LAST && i >= N_NODES) return;
    int half = lane >> 5, c = lane & 31;
    int wid = threadIdx.x >> 6;
    const unsigned* B2 = (const unsigned*)Bm;
    int beg = off[i], end = off[i + 1];
    float e0 = 0.f, e1 = 0.f, e2 = 0.f, e3 = 0.f;
    float e4 = 0.f, e5 = 0.f, e6 = 0.f, e7 = 0.f;
    float o0 = 0.f, o1 = 0.f, o2 = 0.f, o3 = 0.f;
    float o4 = 0.f, o5 = 0.f, o6 = 0.f, o7 = 0.f;
    for (int base = beg; base < end; base += 64) {
        int idx = base + lane;
        int nv = (idx < end) ? nbr[idx] : 0;
        int m = min(64, end - base);
        int tt = 0;
        for (; tt + 16 <= m; tt += 16) {
            int n0 = __shfl(nv, tt + 0 + half);
            int n1 = __shfl(nv, tt + 2 + half);
            int n2 = __shfl(nv, tt + 4 + half);
            int n3 = __shfl(nv, tt + 6 + half);
            int n4 = __shfl(nv, tt + 8 + half);
            int n5 = __shfl(nv, tt + 10 + half);
            int n6 = __shfl(nv, tt + 12 + half);
            int n7 = __shfl(nv, tt + 14 + half);
            unsigned u0 = B2[(long)n0 * 32 + c];
            unsigned u1 = B2[(long)n1 * 32 + c];
            unsigned u2 = B2[(long)n2 * 32 + c];
            unsigned u3 = B2[(long)n3 * 32 + c];
            unsigned u4 = B2[(long)n4 * 32 + c];
            unsigned u5 = B2[(long)n5 * 32 + c];
            unsigned u6 = B2[(long)n6 * 32 + c];
            unsigned u7 = B2[(long)n7 * 32 + c];
            e0 += bflo(u0); o0 += bfhi(u0);
            e1 += bflo(u1); o1 += bfhi(u1);
            e2 += bflo(u2); o2 += bfhi(u2);
            e3 += bflo(u3); o3 += bfhi(u3);
            e4 += bflo(u4); o4 += bfhi(u4);
            e5 += bflo(u5); o5 += bfhi(u5);
            e6 += bflo(u6); o6 += bfhi(u6);
            e7 += bflo(u7); o7 += bfhi(u7);
        }
        for (; tt + 2 <= m; tt += 2) {
            int n0 = __shfl(nv, tt + half);
            unsigned u0 = B2[(long)n0 * 32 + c];
            e0 += bflo(u0); o0 += bfhi(u0);
        }
        if (tt < m) {
            int n0 = __shfl(nv, tt);
            if (half == 0) {
                unsigned u0 = B2[(long)n0 * 32 + c];
                e0 += bflo(u0); o0 += bfhi(u0);
            }
        }
    }
    float es = ((e0 + e1) + (e2 + e3)) + ((e4 + e5) + (e6 + e7));
    float os = ((o0 + o1) + (o2 + o3)) + ((o4 + o5) + (o6 + o7));
    es += __shfl(es, lane ^ 32);
    os += __shfl(os, lane ^ 32);
    if (!LAST) {
        if (half == 0) {
            int deg = end - beg;
            float inv = 1.0f / (float)max(deg, 1);
            float2* Cp = (float2*)(C + (long)i * HD + 2 * c);
            float2 cur = *Cp;
            cur.x += es * inv;
            cur.y += os * inv;
            *Cp = cur;
        }
    } else {
        // fused global-mean-pool: block covers 4 consecutive nodes (sorted batch
        // -> usually same graph); cross-wave reduce in LDS, then 64 atomics.
        __shared__ float red[4][64];
        __shared__ int gid[4];
        if (half == 0) {
            int deg = end - beg;
            float inv = 1.0f / (float)max(deg, 1);
            const float2 cur = *(const float2*)(C + (long)i * HD + 2 * c);
            red[wid][2 * c]     = cur.x + es * inv;
            red[wid][2 * c + 1] = cur.y + os * inv;
        }
        if (lane == 0) gid[wid] = batch[i];
        __syncthreads();
        if (wid == 0) {
            int g0 = gid[0], g1 = gid[1], g2 = gid[2], g3 = gid[3];
            float v0 = red[0][lane], v1 = red[1][lane];
            float v2 = red[2][lane], v3 = red[3][lane];
            if (g0 == g3) {   // sorted batch: g0==g3 implies all equal
                atomicAdd(&cb[g0 * HD + lane],
                          ((v0 + v1) + (v2 + v3)) * invc[g0]);
            } else {
                atomicAdd(&cb[g0 * HD + lane], v0 * invc[g0]);
                atomicAdd(&cb[g1 * HD + lane], v1 * invc[g1]);
                atomicAdd(&cb[g2 * HD + lane], v2 * invc[g2]);
                atomicAdd(&cb[g3 * HD + lane], v3 * invc[g3]);
            }
        }
    }
}

// ---------------- fused head: 3x(lin+BN+tanh) + lin4 ----------------
// Grid barrier: device-scope atomic counter, monotonically increasing rounds.
// NB_HEAD = 64 blocks <= 256 CUs -> all blocks co-resident; bar zeroed by the
// launcher memset every replay.
__device__ __forceinline__ void gbar(int* bar, int round) {
    __syncthreads();
    if (threadIdx.x == 0) {
        __threadfence();
        __hip_atomic_fetch_add(bar, 1, __ATOMIC_RELEASE, __HIP_MEMORY_SCOPE_AGENT);
        int target = round * NB_HEAD;
        while (__hip_atomic_load(bar, __ATOMIC_ACQUIRE, __HIP_MEMORY_SCOPE_AGENT) < target) {}
        __threadfence();
    }
    __syncthreads();
}

// One lin+BN+tanh stage. Block owns C complete output columns -> BN stats are
// block-local (reduction over all 256 rows happens inside the block).
// 256 threads: jj = t % C (column), rg = t / C (rowgroup); C rows per thread.
template <int N, int K, int C>
__device__ __forceinline__ void lin_stage(
        const float* __restrict__ A, const float* __restrict__ W,
        const float* __restrict__ bia, const float* __restrict__ gam,
        const float* __restrict__ bet, float* __restrict__ out,
        float* s_sum, float* s_sq, float* s_m, float* s_sc) {
    const int NRG = 256 / C;
    int t = threadIdx.x;
    int jj = t & (C - 1);
    int rg = t / C;
    int j = blockIdx.x * C + jj;
    float vals[C];
    float bj = bia[j];
    #pragma unroll
    for (int i = 0; i < C; i++) vals[i] = bj;
    #pragma unroll 8
    for (int k = 0; k < K; k += 4) {
        float w0 = W[(k + 0) * N + j];
        float w1 = W[(k + 1) * N + j];
        float w2 = W[(k + 2) * N + j];
        float w3 = W[(k + 3) * N + j];
        #pragma unroll
        for (int i = 0; i < C; i++) {
            int r = rg + NRG * i;
            float4 a = *(const float4*)(A + r * K + k);
            vals[i] = fmaf(a.x, w0, vals[i]);
            vals[i] = fmaf(a.y, w1, vals[i]);
            vals[i] = fmaf(a.z, w2, vals[i]);
            vals[i] = fmaf(a.w, w3, vals[i]);
        }
    }
    float sum = 0.f, sq = 0.f;
    #pragma unroll
    for (int i = 0; i < C; i++) { sum += vals[i]; sq += vals[i] * vals[i]; }
    int lane = t & 63, wid = t >> 6;
    // butterfly across rowgroups within the wave (lanes with equal jj)
    #pragma unroll
    for (int o = C; o < 64; o <<= 1) {
        sum += __shfl_xor(sum, o);
        sq  += __shfl_xor(sq, o);
    }
    if (lane < C) { s_sum[wid * C + lane] = sum; s_sq[wid * C + lane] = sq; }
    __syncthreads();
    if (t < C) {
        float S = s_sum[t] + s_sum[C + t] + s_sum[2 * C + t] + s_sum[3 * C + t];
        float Q = s_sq[t]  + s_sq[C + t]  + s_sq[2 * C + t]  + s_sq[3 * C + t];
        float mean = S * (1.0f / NUM_GRAPHS);
        float var = Q * (1.0f / NUM_GRAPHS) - mean * mean;
        s_m[t] = mean;
        s_sc[t] = rsqrtf(fmaxf(var, 0.f) + EPS) * gam[blockIdx.x * C + t];
    }
    __syncthreads();
    float mean = s_m[jj], sc = s_sc[jj], sh = bet[j];
    #pragma unroll
    for (int i = 0; i < C; i++) {
        out[(rg + NRG * i) * N + j] = tanhf((vals[i] - mean) * sc + sh);
    }
    __syncthreads();
}

__global__ __launch_bounds__(256) void k_head(
        int* bar,
        const float* __restrict__ l1w, const float* __restrict__ l1b,
        const float* __restrict__ g1, const float* __restrict__ be1,
        const float* __restrict__ l2w, const float* __restrict__ l2b,
        const float* __restrict__ g2, const float* __restrict__ be2,
        const float* __restrict__ l3w, const float* __restrict__ l3b,
        const float* __restrict__ g3, const float* __restrict__ be3,
        const float* __restrict__ w4, const float* __restrict__ b4,
        const float* __restrict__ cb, float* __restrict__ m1,
        float* __restrict__ m2, float* __restrict__ m3,
        float* __restrict__ out) {
    __shared__ float s_sum[16], s_sq[16], s_m[4], s_sc[4];
    int t = threadIdx.x;
    lin_stage<256, 64, 4>(cb, l1w, l1b, g1, be1, m1, s_sum, s_sq, s_m, s_sc);
    gbar(bar, 1);
    lin_stage<128, 256, 2>(m1, l2w, l2b, g2, be2, m2, s_sum, s_sq, s_m, s_sc);
    gbar(bar, 2);
    lin_stage<64, 128, 1>(m2, l3w, l3b, g3, be3, m3, s_sum, s_sq, s_m, s_sc);
    gbar(bar, 3);
    // lin4: 4 rows per block, 10 outputs per row
    if (t < 40) {
        int q = t / 10, jf = t % 10;
        int row = blockIdx.x * 4 + q;
        const float* rp = m3 + row * 64;
        float s = b4[jf];
        #pragma unroll
        for (int k = 0; k < 64; k++) s = fmaf(rp[k], w4[k * 10 + jf], s);
        out[row * 10 + jf] = s;
    }
}

extern "C" void kernel_launch(void* const* d_in, const int* in_sizes, int n_in,
                              void* d_out, int out_size, void* d_ws, size_t ws_size,
                              hipStream_t stream) {
    const float* x     = (const float*)d_in[0];
    const int*   ei    = (const int*) d_in[1];
    const int*   batch = (const int*) d_in[2];
    const float *W1l = (const float*)d_in[3],  *b1l = (const float*)d_in[4],  *W1r = (const float*)d_in[5];
    const float *W2l = (const float*)d_in[6],  *b2l = (const float*)d_in[7],  *W2r = (const float*)d_in[8];
    const float *W3l = (const float*)d_in[9],  *b3l = (const float*)d_in[10], *W3r = (const float*)d_in[11];
    const float *lin1_w = (const float*)d_in[12], *lin1_b = (const float*)d_in[13];
    const float *g1 = (const float*)d_in[14], *be1 = (const float*)d_in[15];
    const float *lin2_w = (const float*)d_in[16], *lin2_b = (const float*)d_in[17];
    const float *g2 = (const float*)d_in[18], *be2 = (const float*)d_in[19];
    const float *lin3_w = (const float*)d_in[20], *lin3_b = (const float*)d_in[21];
    const float *g3 = (const float*)d_in[22], *be3 = (const float*)d_in[23];
    const float *lin4_w = (const float*)d_in[24], *lin4_b = (const float*)d_in[25];

    const int* srcp = ei;
    const int* dstp = ei + N_EDGES;

    // ---- workspace layout ----
    const long NF = (long)N_NODES * HD;              // 3,200,000
    char* wsb  = (char*)d_ws;
    int*  cnti = (int*)wsb;                          // 50,048
    int*  bar  = cnti + 50048;                       // 8 (zeroed with cnti)
    int*  pos  = bar  + 8;                           // 800,000
    int*  off  = pos  + 800000;                      // 50,056
    int*  nbr  = off  + 50056;                       // 800,000
    int*  bsum = nbr  + 800000;                      // 256
    int*  gb   = bsum + 256;                         // 264 (257 used)
    float* invc = (float*)(gb + 264);                // 256
    bf16* B    = (bf16*)(invc + 256);                // 3,200,000 bf16
    float* H1  = (float*)(B + NF);                   // 3,200,000
    float* H2  = H1  + NF;                           // 3,200,000
    float* cb  = H2  + NF;                           // 16,384
    float* m1  = cb  + NUM_GRAPHS * HD;              // 65,536
    float* m2  = m1  + NUM_GRAPHS * 256;             // 32,768
    float* m3  = m2  + NUM_GRAPHS * 128;             // 16,384
    float* endp= m3  + NUM_GRAPHS * 64;

    const size_t NEED = (size_t)((char*)endp - wsb);
    if (ws_size < NEED) {
        k_diag<<<(out_size + 255) / 256, 256, 0, stream>>>((float*)d_out, out_size,
                                                           (float)(ws_size >> 20));
        return;
    }

    const int TB = 256;
    const int gNE = (N_EDGES + TB - 1) / TB;
    const int gNF = (int)((NF + TB - 1) / TB);        // 12500 (= exactly 50000 nodes)
    const int gXB = (N_NODES + 31) / 32;              // 1563

    hipMemsetAsync(cnti, 0, (50048 + 8) * sizeof(int), stream);
    hipMemsetAsync(cb, 0, NUM_GRAPHS * HD * sizeof(float), stream);

    // ---- CSR build (+ graph bounds) ----
    k_count<<<gNE, TB, 0, stream>>>(dstp, batch, cnti, pos, gb);
    k_scan1<<<SCAN_NB, TB, 0, stream>>>(cnti, off, bsum);
    k_scan3<<<SCAN_NB, TB, 0, stream>>>(off, bsum, gb, invc);
    k_fill<<<gNE, TB, 0, stream>>>(srcp, dstp, off, pos, nbr);

    // ---- SAGE layers (bf16 messages, pairwise gather) ----
    k_xform3<IN_DIM><<<gXB, TB, 0, stream>>>(x, W1l, W1r, b1l, B, H1);
    k_gather<false><<<gNF, TB, 0, stream>>>(off, nbr, B, H1, batch, invc, cb);
    k_xform3<HD><<<gXB, TB, 0, stream>>>(H1, W2l, W2r, b2l, B, H2);
    k_gather<false><<<gNF, TB, 0, stream>>>(off, nbr, B, H2, batch, invc, cb);
    k_xform3<HD><<<gXB, TB, 0, stream>>>(H2, W3l, W3r, b3l, B, H1);
    // last gather: fused global-mean-pool into cb (H1 never written back)
    k_gather<true><<<gNF, TB, 0, stream>>>(off, nbr, B, H1, batch, invc, cb);

    // ---- fused head: lin1/2/3 (+BN+tanh) + lin4, one dispatch ----
    k_head<<<NB_HEAD, TB, 0, stream>>>(bar,
                                       lin1_w, lin1_b, g1, be1,
                                       lin2_w, lin2_b, g2, be2,
                                       lin3_w, lin3_b, g3, be3,
                                       lin4_w, lin4_b,
                                       cb, m1, m2, m3, (float*)d_out);
}

// Round 3
// 395.558 us; speedup vs baseline: 1.1842x; 1.0141x over previous
//
#include <hip/hip_runtime.h>
#include <hip/hip_bf16.h>

#define N_NODES   50000
#define N_EDGES   800000
#define NUM_GRAPHS 256
#define IN_DIM    128
#define HD        64
#define EPS       1e-5f
#define SCAN_NB   196      // ceil(50000/256)
#define NB_HEAD   64       // head kernel grid (must be <= CU count for co-residency)

typedef __hip_bfloat16 bf16;

// ---------------- diagnostics ----------------
__global__ void k_diag(float* __restrict__ out, int n, float v) {
    int t = blockIdx.x * 256 + threadIdx.x;
    if (t < n) out[t] = v;
}

// ---------------- CSR build (+ graph bounds for pooling) ----------------
__global__ void k_count(const int* __restrict__ dst, const int* __restrict__ batch,
                        int* __restrict__ cnti, int* __restrict__ pos,
                        int* __restrict__ gb) {
    int e = blockIdx.x * 256 + threadIdx.x;
    if (e < N_EDGES) pos[e] = atomicAdd(&cnti[dst[e]], 1);
    // graph bounds: gb[g] = first node index with batch >= g (batch is sorted)
    if (e < N_NODES) {
        int bg = batch[e];
        int bnext = (e + 1 < N_NODES) ? batch[e + 1] : NUM_GRAPHS;
        if (e == 0) {
            for (int g = 0; g <= bg; ++g) gb[g] = 0;
        }
        for (int g = bg + 1; g <= bnext; ++g) gb[g] = e + 1;
    }
}

__global__ void k_scan1(const int* __restrict__ cnti, int* __restrict__ off,
                        int* __restrict__ bsum) {
    __shared__ int wsum[4];
    int idx = blockIdx.x * 256 + threadIdx.x;
    int lane = threadIdx.x & 63, wid = threadIdx.x >> 6;
    int v = (idx < N_NODES) ? cnti[idx] : 0;
    int s = v;
    #pragma unroll
    for (int o = 1; o < 64; o <<= 1) {
        int u = __shfl_up(s, o);
        if (lane >= o) s += u;
    }
    if (lane == 63) wsum[wid] = s;
    __syncthreads();
    int wbase = 0;
    #pragma unroll
    for (int w = 0; w < 4; w++) wbase += (w < wid) ? wsum[w] : 0;
    if (idx < N_NODES) off[idx] = wbase + s - v;
    if (threadIdx.x == 255) bsum[blockIdx.x] = wbase + s;
}

__global__ void k_scan3(int* __restrict__ off, const int* __restrict__ bsum,
                        const int* __restrict__ gb, float* __restrict__ invc) {
    __shared__ int wsum[4];
    __shared__ int spre;
    int lane = threadIdx.x & 63, wid = threadIdx.x >> 6;
    int v = (threadIdx.x < blockIdx.x) ? bsum[threadIdx.x] : 0;
    #pragma unroll
    for (int o = 32; o > 0; o >>= 1) v += __shfl_down(v, o);
    if (lane == 0) wsum[wid] = v;
    __syncthreads();
    if (threadIdx.x == 0) spre = wsum[0] + wsum[1] + wsum[2] + wsum[3];
    __syncthreads();
    int pre = spre;
    int idx = blockIdx.x * 256 + threadIdx.x;
    if (idx < N_NODES) off[idx] += pre;
    else if (idx == N_NODES) off[N_NODES] = N_EDGES;
    // per-graph 1/count for fused pooling (gb ready since k_count)
    if (blockIdx.x == 0 && threadIdx.x < NUM_GRAPHS) {
        int c0 = gb[threadIdx.x], c1 = gb[threadIdx.x + 1];
        invc[threadIdx.x] = 1.0f / (float)max(c1 - c0, 1);
    }
}

__global__ void k_fill(const int* __restrict__ src, const int* __restrict__ dst,
                       const int* __restrict__ off, const int* __restrict__ pos,
                       int* __restrict__ nbr) {
    int e = blockIdx.x * 256 + threadIdx.x;
    if (e >= N_EDGES) return;
    int d = dst[e];
    nbr[off[d] + pos[e]] = src[e];
}

// ---- fused transform, LDS-staged X tile: B(bf16) = X@Wl ; C = X@Wr + bl ----
template <int K>
__global__ __launch_bounds__(256) void k_xform3(
        const float* __restrict__ X, const float* __restrict__ Wl,
        const float* __restrict__ Wr, const float* __restrict__ bl,
        bf16* __restrict__ B, float* __restrict__ C) {
    __shared__ float tile[32 * K];
    const int NPW = 8;
    int nodes0 = blockIdx.x * 32;
    {
        const int total4 = 32 * K / 4;
        int nmax4 = (N_NODES - nodes0) * K / 4;
        const float4* Xg = (const float4*)(X + (long)nodes0 * K);
        float4* tg = (float4*)tile;
        for (int idx = threadIdx.x; idx < total4; idx += 256) {
            float4 v = make_float4(0.f, 0.f, 0.f, 0.f);
            if (idx < nmax4) v = Xg[idx];
            tg[idx] = v;
        }
    }
    __syncthreads();
    int wave = threadIdx.x >> 6, j = threadIdx.x & 63;
    long base = (long)nodes0 + wave * NPW;
    if (base >= N_NODES) return;
    float accB[NPW], accC[NPW];
    #pragma unroll
    for (int n = 0; n < NPW; n++) { accB[n] = 0.f; accC[n] = 0.f; }
    const float* Xs = tile + (wave * NPW) * K;
    for (int kc = 0; kc < K; kc += 4) {
        float wl0 = Wl[(kc + 0) * HD + j], wr0 = Wr[(kc + 0) * HD + j];
        float wl1 = Wl[(kc + 1) * HD + j], wr1 = Wr[(kc + 1) * HD + j];
        float wl2 = Wl[(kc + 2) * HD + j], wr2 = Wr[(kc + 2) * HD + j];
        float wl3 = Wl[(kc + 3) * HD + j], wr3 = Wr[(kc + 3) * HD + j];
        #pragma unroll
        for (int n = 0; n < NPW; n++) {
            float4 xv = *(const float4*)(Xs + n * K + kc);
            accB[n] = fmaf(xv.x, wl0, accB[n]);
            accC[n] = fmaf(xv.x, wr0, accC[n]);
            accB[n] = fmaf(xv.y, wl1, accB[n]);
            accC[n] = fmaf(xv.y, wr1, accC[n]);
            accB[n] = fmaf(xv.z, wl2, accB[n]);
            accC[n] = fmaf(xv.z, wr2, accC[n]);
            accB[n] = fmaf(xv.w, wl3, accB[n]);
            accC[n] = fmaf(xv.w, wr3, accC[n]);
        }
    }
    float bb = bl[j];
    int nact = (int)min((long)NPW, (long)N_NODES - base);
    for (int n = 0; n < nact; n++) {
        long i = base + n;
        B[i * HD + j] = __float2bfloat16(accB[n]);
        C[i * HD + j] = accC[n] + bb;
    }
}

__device__ __forceinline__ float bflo(unsigned u) { return __uint_as_float(u << 16); }
__device__ __forceinline__ float bfhi(unsigned u) { return __uint_as_float(u & 0xffff0000u); }

// ---- CSR gather, pairwise (2 neighbor rows per wave-load) ----
// LAST=true: instead of writing C, fuse the global mean pool: accumulate
// (C_row + mean_aggr) * invc[batch[i]] into cb via device-scope atomics.
template <bool LAST>
__global__ void k_gather(const int* __restrict__ off, const int* __restrict__ nbr,
                         const bf16* __restrict__ Bm, float* __restrict__ C,
                         const int* __restrict__ batch, const float* __restrict__ invc,
                         float* __restrict__ cb) {
    int t = blockIdx.x * 256 + threadIdx.x;
    int i = t >> 6, lane = t & 63;
    if (!LAST && i >= N_NODES) return;
    int half = lane >> 5, c = lane & 31;
    int wid = threadIdx.x >> 6;
    const unsigned* B2 = (const unsigned*)Bm;
    int beg = off[i], end = off[i + 1];
    float e0 = 0.f, e1 = 0.f, e2 = 0.f, e3 = 0.f;
    float e4 = 0.f, e5 = 0.f, e6 = 0.f, e7 = 0.f;
    float o0 = 0.f, o1 = 0.f, o2 = 0.f, o3 = 0.f;
    float o4 = 0.f, o5 = 0.f, o6 = 0.f, o7 = 0.f;
    for (int base = beg; base < end; base += 64) {
        int idx = base + lane;
        int nv = (idx < end) ? nbr[idx] : 0;
        int m = min(64, end - base);
        int tt = 0;
        for (; tt + 16 <= m; tt += 16) {
            int n0 = __shfl(nv, tt + 0 + half);
            int n1 = __shfl(nv, tt + 2 + half);
            int n2 = __shfl(nv, tt + 4 + half);
            int n3 = __shfl(nv, tt + 6 + half);
            int n4 = __shfl(nv, tt + 8 + half);
            int n5 = __shfl(nv, tt + 10 + half);
            int n6 = __shfl(nv, tt + 12 + half);
            int n7 = __shfl(nv, tt + 14 + half);
            unsigned u0 = B2[(long)n0 * 32 + c];
            unsigned u1 = B2[(long)n1 * 32 + c];
            unsigned u2 = B2[(long)n2 * 32 + c];
            unsigned u3 = B2[(long)n3 * 32 + c];
            unsigned u4 = B2[(long)n4 * 32 + c];
            unsigned u5 = B2[(long)n5 * 32 + c];
            unsigned u6 = B2[(long)n6 * 32 + c];
            unsigned u7 = B2[(long)n7 * 32 + c];
            e0 += bflo(u0); o0 += bfhi(u0);
            e1 += bflo(u1); o1 += bfhi(u1);
            e2 += bflo(u2); o2 += bfhi(u2);
            e3 += bflo(u3); o3 += bfhi(u3);
            e4 += bflo(u4); o4 += bfhi(u4);
            e5 += bflo(u5); o5 += bfhi(u5);
            e6 += bflo(u6); o6 += bfhi(u6);
            e7 += bflo(u7); o7 += bfhi(u7);
        }
        for (; tt + 2 <= m; tt += 2) {
            int n0 = __shfl(nv, tt + half);
            unsigned u0 = B2[(long)n0 * 32 + c];
            e0 += bflo(u0); o0 += bfhi(u0);
        }
        if (tt < m) {
            int n0 = __shfl(nv, tt);
            if (half == 0) {
                unsigned u0 = B2[(long)n0 * 32 + c];
                e0 += bflo(u0); o0 += bfhi(u0);
            }
        }
    }
    float es = ((e0 + e1) + (e2 + e3)) + ((e4 + e5) + (e6 + e7));
    float os = ((o0 + o1) + (o2 + o3)) + ((o4 + o5) + (o6 + o7));
    es += __shfl(es, lane ^ 32);
    os += __shfl(os, lane ^ 32);
    if (!LAST) {
        if (half == 0) {
            int deg = end - beg;
            float inv = 1.0f / (float)max(deg, 1);
            float2* Cp = (float2*)(C + (long)i * HD + 2 * c);
            float2 cur = *Cp;
            cur.x += es * inv;
            cur.y += os * inv;
            *Cp = cur;
        }
    } else {
        // fused global-mean-pool: block covers 4 consecutive nodes (sorted batch
        // -> usually same graph); cross-wave reduce in LDS, then 64 atomics.
        __shared__ float red[4][64];
        __shared__ int gid[4];
        if (half == 0) {
            int deg = end - beg;
            float inv = 1.0f / (float)max(deg, 1);
            const float2 cur = *(const float2*)(C + (long)i * HD + 2 * c);
            red[wid][2 * c]     = cur.x + es * inv;
            red[wid][2 * c + 1] = cur.y + os * inv;
        }
        if (lane == 0) gid[wid] = batch[i];
        __syncthreads();
        if (wid == 0) {
            int g0 = gid[0], g1 = gid[1], g2 = gid[2], g3 = gid[3];
            float v0 = red[0][lane], v1 = red[1][lane];
            float v2 = red[2][lane], v3 = red[3][lane];
            if (g0 == g3) {   // sorted batch: g0==g3 implies all equal
                atomicAdd(&cb[g0 * HD + lane],
                          ((v0 + v1) + (v2 + v3)) * invc[g0]);
            } else {
                atomicAdd(&cb[g0 * HD + lane], v0 * invc[g0]);
                atomicAdd(&cb[g1 * HD + lane], v1 * invc[g1]);
                atomicAdd(&cb[g2 * HD + lane], v2 * invc[g2]);
                atomicAdd(&cb[g3 * HD + lane], v3 * invc[g3]);
            }
        }
    }
}

// ---------------- fused head, row-partitioned ----------------
// Block r owns graphs 4r..4r+3 end-to-end; intermediates stay in LDS.
// Only BN column-statistics cross blocks, via device-scope f32 atomics
// (gstat zeroed by launcher memset) + acq/rel grid barrier (no threadfence:
// atomics are memory-side coherent; barrier release/acquire orders them).
__device__ __forceinline__ void gbar(int* bar, int round) {
    __syncthreads();
    if (threadIdx.x == 0) {
        __hip_atomic_fetch_add(bar, 1, __ATOMIC_ACQ_REL, __HIP_MEMORY_SCOPE_AGENT);
        int target = round * NB_HEAD;
        while (__hip_atomic_load(bar, __ATOMIC_ACQUIRE, __HIP_MEMORY_SCOPE_AGENT) < target) {}
    }
    __syncthreads();
}

__device__ __forceinline__ float ag_load(const float* p) {
    return __hip_atomic_load(p, __ATOMIC_RELAXED, __HIP_MEMORY_SCOPE_AGENT);
}

__global__ __launch_bounds__(256) void k_head(
        int* bar, float* __restrict__ gstat,
        const float* __restrict__ l1w, const float* __restrict__ l1b,
        const float* __restrict__ g1, const float* __restrict__ be1,
        const float* __restrict__ l2w, const float* __restrict__ l2b,
        const float* __restrict__ g2, const float* __restrict__ be2,
        const float* __restrict__ l3w, const float* __restrict__ l3b,
        const float* __restrict__ g3, const float* __restrict__ be3,
        const float* __restrict__ w4, const float* __restrict__ b4,
        const float* __restrict__ cb, float* __restrict__ out) {
    __shared__ float A1[4][64];    // cb rows (lin1 input)
    __shared__ float A2[4][256];   // lin1 output
    __shared__ float A3[4][128];   // lin2 output
    __shared__ float M3[4][64];    // lin3 output
    float* gs1 = gstat;            // [256] lin1 col sums
    float* gq1 = gstat + 256;      // [256]
    float* gs2 = gstat + 512;      // [128]
    float* gq2 = gstat + 640;      // [128]
    float* gs3 = gstat + 768;      // [64]
    float* gq3 = gstat + 832;      // [64]
    int t = threadIdx.x;
    int r0 = blockIdx.x * 4;       // first graph row owned by this block

    // load own 4 rows of cb (complete: kernel boundary after gather atomics)
    {
        int r = t >> 6, lane = t & 63;
        A1[r][lane] = cb[(r0 + r) * HD + lane];
    }
    __syncthreads();

    // ---- lin1: K=64 -> N=256; thread t owns column t for all 4 rows ----
    float v1[4];
    {
        int j = t;
        float bj = l1b[j];
        v1[0] = bj; v1[1] = bj; v1[2] = bj; v1[3] = bj;
        #pragma unroll 4
        for (int k = 0; k < 64; k++) {
            float w = l1w[k * 256 + j];
            v1[0] = fmaf(A1[0][k], w, v1[0]);
            v1[1] = fmaf(A1[1][k], w, v1[1]);
            v1[2] = fmaf(A1[2][k], w, v1[2]);
            v1[3] = fmaf(A1[3][k], w, v1[3]);
        }
        float s = (v1[0] + v1[1]) + (v1[2] + v1[3]);
        float q = (v1[0] * v1[0] + v1[1] * v1[1]) + (v1[2] * v1[2] + v1[3] * v1[3]);
        atomicAdd(&gs1[j], s);
        atomicAdd(&gq1[j], q);
    }
    gbar(bar, 1);
    {
        int j = t;
        float S = ag_load(&gs1[j]), Q = ag_load(&gq1[j]);
        float mean = S * (1.0f / NUM_GRAPHS);
        float var = Q * (1.0f / NUM_GRAPHS) - mean * mean;
        float sc = rsqrtf(fmaxf(var, 0.f) + EPS) * g1[j];
        float sh = be1[j];
        #pragma unroll
        for (int r = 0; r < 4; r++)
            A2[r][j] = tanhf((v1[r] - mean) * sc + sh);
    }
    __syncthreads();

    // ---- lin2: K=256 -> N=128; thread = (col j, rowpair rq) ----
    float v2[2];
    int j2 = t & 127, rq2 = t >> 7;           // rows 2*rq2, 2*rq2+1
    {
        float bj = l2b[j2];
        v2[0] = bj; v2[1] = bj;
        #pragma unroll 4
        for (int k = 0; k < 256; k++) {
            float w = l2w[k * 128 + j2];
            v2[0] = fmaf(A2[2 * rq2 + 0][k], w, v2[0]);
            v2[1] = fmaf(A2[2 * rq2 + 1][k], w, v2[1]);
        }
        atomicAdd(&gs2[j2], v2[0] + v2[1]);
        atomicAdd(&gq2[j2], v2[0] * v2[0] + v2[1] * v2[1]);
    }
    gbar(bar, 2);
    {
        float S = ag_load(&gs2[j2]), Q = ag_load(&gq2[j2]);
        float mean = S * (1.0f / NUM_GRAPHS);
        float var = Q * (1.0f / NUM_GRAPHS) - mean * mean;
        float sc = rsqrtf(fmaxf(var, 0.f) + EPS) * g2[j2];
        float sh = be2[j2];
        A3[2 * rq2 + 0][j2] = tanhf((v2[0] - mean) * sc + sh);
        A3[2 * rq2 + 1][j2] = tanhf((v2[1] - mean) * sc + sh);
    }
    __syncthreads();

    // ---- lin3: K=128 -> N=64; thread = (col j, row rq) ----
    float v3;
    int j3 = t & 63, rq3 = t >> 6;            // row rq3
    {
        float bj = l3b[j3];
        v3 = bj;
        #pragma unroll 4
        for (int k = 0; k < 128; k++) {
            float w = l3w[k * 64 + j3];
            v3 = fmaf(A3[rq3][k], w, v3);
        }
        atomicAdd(&gs3[j3], v3);
        atomicAdd(&gq3[j3], v3 * v3);
    }
    gbar(bar, 3);
    {
        float S = ag_load(&gs3[j3]), Q = ag_load(&gq3[j3]);
        float mean = S * (1.0f / NUM_GRAPHS);
        float var = Q * (1.0f / NUM_GRAPHS) - mean * mean;
        float sc = rsqrtf(fmaxf(var, 0.f) + EPS) * g3[j3];
        float sh = be3[j3];
        M3[rq3][j3] = tanhf((v3 - mean) * sc + sh);
    }
    __syncthreads();

    // ---- lin4: 4 rows x 10 outputs, all local ----
    if (t < 40) {
        int q = t / 10, jf = t % 10;
        const float* rp = M3[q];
        float s = b4[jf];
        #pragma unroll
        for (int k = 0; k < 64; k++) s = fmaf(rp[k], w4[k * 10 + jf], s);
        out[(r0 + q) * 10 + jf] = s;
    }
}

extern "C" void kernel_launch(void* const* d_in, const int* in_sizes, int n_in,
                              void* d_out, int out_size, void* d_ws, size_t ws_size,
                              hipStream_t stream) {
    const float* x     = (const float*)d_in[0];
    const int*   ei    = (const int*) d_in[1];
    const int*   batch = (const int*) d_in[2];
    const float *W1l = (const float*)d_in[3],  *b1l = (const float*)d_in[4],  *W1r = (const float*)d_in[5];
    const float *W2l = (const float*)d_in[6],  *b2l = (const float*)d_in[7],  *W2r = (const float*)d_in[8];
    const float *W3l = (const float*)d_in[9],  *b3l = (const float*)d_in[10], *W3r = (const float*)d_in[11];
    const float *lin1_w = (const float*)d_in[12], *lin1_b = (const float*)d_in[13];
    const float *g1 = (const float*)d_in[14], *be1 = (const float*)d_in[15];
    const float *lin2_w = (const float*)d_in[16], *lin2_b = (const float*)d_in[17];
    const float *g2 = (const float*)d_in[18], *be2 = (const float*)d_in[19];
    const float *lin3_w = (const float*)d_in[20], *lin3_b = (const float*)d_in[21];
    const float *g3 = (const float*)d_in[22], *be3 = (const float*)d_in[23];
    const float *lin4_w = (const float*)d_in[24], *lin4_b = (const float*)d_in[25];

    const int* srcp = ei;
    const int* dstp = ei + N_EDGES;

    // ---- workspace layout ----
    const long NF = (long)N_NODES * HD;              // 3,200,000
    char* wsb  = (char*)d_ws;
    int*  cnti = (int*)wsb;                          // 50,048
    int*  bar  = cnti + 50048;                       // 8
    float* gstat = (float*)(bar + 8);                // 896 (zeroed with cnti)
    int*  pos  = (int*)(gstat + 896);                // 800,000
    int*  off  = pos  + 800000;                      // 50,056
    int*  nbr  = off  + 50056;                       // 800,000
    int*  bsum = nbr  + 800000;                      // 256
    int*  gb   = bsum + 256;                         // 264 (257 used)
    float* invc = (float*)(gb + 264);                // 256
    bf16* B    = (bf16*)(invc + 256);                // 3,200,000 bf16
    float* H1  = (float*)(B + NF);                   // 3,200,000
    float* H2  = H1  + NF;                           // 3,200,000
    float* cb  = H2  + NF;                           // 16,384
    float* endp= cb  + NUM_GRAPHS * HD;

    const size_t NEED = (size_t)((char*)endp - wsb);
    if (ws_size < NEED) {
        k_diag<<<(out_size + 255) / 256, 256, 0, stream>>>((float*)d_out, out_size,
                                                           (float)(ws_size >> 20));
        return;
    }

    const int TB = 256;
    const int gNE = (N_EDGES + TB - 1) / TB;
    const int gNF = (int)((NF + TB - 1) / TB);        // 12500 (= exactly 50000 nodes)
    const int gXB = (N_NODES + 31) / 32;              // 1563

    hipMemsetAsync(cnti, 0, (50048 + 8 + 896) * sizeof(int), stream);
    hipMemsetAsync(cb, 0, NUM_GRAPHS * HD * sizeof(float), stream);

    // ---- CSR build (+ graph bounds) ----
    k_count<<<gNE, TB, 0, stream>>>(dstp, batch, cnti, pos, gb);
    k_scan1<<<SCAN_NB, TB, 0, stream>>>(cnti, off, bsum);
    k_scan3<<<SCAN_NB, TB, 0, stream>>>(off, bsum, gb, invc);
    k_fill<<<gNE, TB, 0, stream>>>(srcp, dstp, off, pos, nbr);

    // ---- SAGE layers (bf16 messages, pairwise gather) ----
    k_xform3<IN_DIM><<<gXB, TB, 0, stream>>>(x, W1l, W1r, b1l, B, H1);
    k_gather<false><<<gNF, TB, 0, stream>>>(off, nbr, B, H1, batch, invc, cb);
    k_xform3<HD><<<gXB, TB, 0, stream>>>(H1, W2l, W2r, b2l, B, H2);
    k_gather<false><<<gNF, TB, 0, stream>>>(off, nbr, B, H2, batch, invc, cb);
    k_xform3<HD><<<gXB, TB, 0, stream>>>(H2, W3l, W3r, b3l, B, H1);
    // last gather: fused global-mean-pool into cb (H1 never written back)
    k_gather<true><<<gNF, TB, 0, stream>>>(off, nbr, B, H1, batch, invc, cb);

    // ---- fused head: row-partitioned, LDS-resident intermediates ----
    k_head<<<NB_HEAD, TB, 0, stream>>>(bar, gstat,
                                       lin1_w, lin1_b, g1, be1,
                                       lin2_w, lin2_b, g2, be2,
                                       lin3_w, lin3_b, g3, be3,
                                       lin4_w, lin4_b,
                                       cb, (float*)d_out);
}

// Round 4
// 379.284 us; speedup vs baseline: 1.2350x; 1.0429x over previous
//
#include <hip/hip_runtime.h>
#include <hip/hip_bf16.h>

#define N_NODES   50000
#define N_EDGES   800000
#define NUM_GRAPHS 256
#define IN_DIM    128
#define HD        64
#define EPS       1e-5f
#define SCAN_NB   196      // ceil(50000/256)
#define NB_HEAD   64       // head kernel grid (must be <= CU count for co-residency)

typedef __hip_bfloat16 bf16;

// ---------------- diagnostics ----------------
__global__ void k_diag(float* __restrict__ out, int n, float v) {
    int t = blockIdx.x * 256 + threadIdx.x;
    if (t < n) out[t] = v;
}

// ---------------- CSR build (+ graph bounds for pooling) ----------------
__global__ void k_count(const int* __restrict__ dst, const int* __restrict__ batch,
                        int* __restrict__ cnti, int* __restrict__ pos,
                        int* __restrict__ gb) {
    int e = blockIdx.x * 256 + threadIdx.x;
    if (e < N_EDGES) pos[e] = atomicAdd(&cnti[dst[e]], 1);
    // graph bounds: gb[g] = first node index with batch >= g (batch is sorted)
    if (e < N_NODES) {
        int bg = batch[e];
        int bnext = (e + 1 < N_NODES) ? batch[e + 1] : NUM_GRAPHS;
        if (e == 0) {
            for (int g = 0; g <= bg; ++g) gb[g] = 0;
        }
        for (int g = bg + 1; g <= bnext; ++g) gb[g] = e + 1;
    }
}

__global__ void k_scan1(const int* __restrict__ cnti, int* __restrict__ off,
                        int* __restrict__ bsum) {
    __shared__ int wsum[4];
    int idx = blockIdx.x * 256 + threadIdx.x;
    int lane = threadIdx.x & 63, wid = threadIdx.x >> 6;
    int v = (idx < N_NODES) ? cnti[idx] : 0;
    int s = v;
    #pragma unroll
    for (int o = 1; o < 64; o <<= 1) {
        int u = __shfl_up(s, o);
        if (lane >= o) s += u;
    }
    if (lane == 63) wsum[wid] = s;
    __syncthreads();
    int wbase = 0;
    #pragma unroll
    for (int w = 0; w < 4; w++) wbase += (w < wid) ? wsum[w] : 0;
    if (idx < N_NODES) off[idx] = wbase + s - v;
    if (threadIdx.x == 255) bsum[blockIdx.x] = wbase + s;
}

__global__ void k_scan3(int* __restrict__ off, const int* __restrict__ bsum,
                        const int* __restrict__ gb, float* __restrict__ invc) {
    __shared__ int wsum[4];
    __shared__ int spre;
    int lane = threadIdx.x & 63, wid = threadIdx.x >> 6;
    int v = (threadIdx.x < blockIdx.x) ? bsum[threadIdx.x] : 0;
    #pragma unroll
    for (int o = 32; o > 0; o >>= 1) v += __shfl_down(v, o);
    if (lane == 0) wsum[wid] = v;
    __syncthreads();
    if (threadIdx.x == 0) spre = wsum[0] + wsum[1] + wsum[2] + wsum[3];
    __syncthreads();
    int pre = spre;
    int idx = blockIdx.x * 256 + threadIdx.x;
    if (idx < N_NODES) off[idx] += pre;
    else if (idx == N_NODES) off[N_NODES] = N_EDGES;
    // per-graph 1/count for fused pooling (gb ready since k_count)
    if (blockIdx.x == 0 && threadIdx.x < NUM_GRAPHS) {
        int c0 = gb[threadIdx.x], c1 = gb[threadIdx.x + 1];
        invc[threadIdx.x] = 1.0f / (float)max(c1 - c0, 1);
    }
}

__global__ void k_fill(const int* __restrict__ src, const int* __restrict__ dst,
                       const int* __restrict__ off, const int* __restrict__ pos,
                       int* __restrict__ nbr) {
    int e = blockIdx.x * 256 + threadIdx.x;
    if (e >= N_EDGES) return;
    int d = dst[e];
    nbr[off[d] + pos[e]] = src[e];
}

// ---- fused transform, LDS-staged X tile: B(bf16) = X@Wl ; C = X@Wr + bl ----
template <int K>
__global__ __launch_bounds__(256) void k_xform3(
        const float* __restrict__ X, const float* __restrict__ Wl,
        const float* __restrict__ Wr, const float* __restrict__ bl,
        bf16* __restrict__ B, float* __restrict__ C) {
    __shared__ float tile[32 * K];
    const int NPW = 8;
    int nodes0 = blockIdx.x * 32;
    {
        const int total4 = 32 * K / 4;
        int nmax4 = (N_NODES - nodes0) * K / 4;
        const float4* Xg = (const float4*)(X + (long)nodes0 * K);
        float4* tg = (float4*)tile;
        for (int idx = threadIdx.x; idx < total4; idx += 256) {
            float4 v = make_float4(0.f, 0.f, 0.f, 0.f);
            if (idx < nmax4) v = Xg[idx];
            tg[idx] = v;
        }
    }
    __syncthreads();
    int wave = threadIdx.x >> 6, j = threadIdx.x & 63;
    long base = (long)nodes0 + wave * NPW;
    if (base >= N_NODES) return;
    float accB[NPW], accC[NPW];
    #pragma unroll
    for (int n = 0; n < NPW; n++) { accB[n] = 0.f; accC[n] = 0.f; }
    const float* Xs = tile + (wave * NPW) * K;
    for (int kc = 0; kc < K; kc += 4) {
        float wl0 = Wl[(kc + 0) * HD + j], wr0 = Wr[(kc + 0) * HD + j];
        float wl1 = Wl[(kc + 1) * HD + j], wr1 = Wr[(kc + 1) * HD + j];
        float wl2 = Wl[(kc + 2) * HD + j], wr2 = Wr[(kc + 2) * HD + j];
        float wl3 = Wl[(kc + 3) * HD + j], wr3 = Wr[(kc + 3) * HD + j];
        #pragma unroll
        for (int n = 0; n < NPW; n++) {
            float4 xv = *(const float4*)(Xs + n * K + kc);
            accB[n] = fmaf(xv.x, wl0, accB[n]);
            accC[n] = fmaf(xv.x, wr0, accC[n]);
            accB[n] = fmaf(xv.y, wl1, accB[n]);
            accC[n] = fmaf(xv.y, wr1, accC[n]);
            accB[n] = fmaf(xv.z, wl2, accB[n]);
            accC[n] = fmaf(xv.z, wr2, accC[n]);
            accB[n] = fmaf(xv.w, wl3, accB[n]);
            accC[n] = fmaf(xv.w, wr3, accC[n]);
        }
    }
    float bb = bl[j];
    int nact = (int)min((long)NPW, (long)N_NODES - base);
    for (int n = 0; n < nact; n++) {
        long i = base + n;
        B[i * HD + j] = __float2bfloat16(accB[n]);
        C[i * HD + j] = accC[n] + bb;
    }
}

__device__ __forceinline__ float bflo(unsigned u) { return __uint_as_float(u << 16); }
__device__ __forceinline__ float bfhi(unsigned u) { return __uint_as_float(u & 0xffff0000u); }

// ---- CSR gather, pairwise (2 neighbor rows per wave-load) ----
// LAST=true: instead of writing C, fuse the global mean pool: accumulate
// (C_row + mean_aggr) * invc[batch[i]] into cb via device-scope atomics.
template <bool LAST>
__global__ void k_gather(const int* __restrict__ off, const int* __restrict__ nbr,
                         const bf16* __restrict__ Bm, float* __restrict__ C,
                         const int* __restrict__ batch, const float* __restrict__ invc,
                         float* __restrict__ cb) {
    int t = blockIdx.x * 256 + threadIdx.x;
    int i = t >> 6, lane = t & 63;
    if (!LAST && i >= N_NODES) return;
    int half = lane >> 5, c = lane & 31;
    int wid = threadIdx.x >> 6;
    const unsigned* B2 = (const unsigned*)Bm;
    int beg = off[i], end = off[i + 1];
    float e0 = 0.f, e1 = 0.f, e2 = 0.f, e3 = 0.f;
    float e4 = 0.f, e5 = 0.f, e6 = 0.f, e7 = 0.f;
    float o0 = 0.f, o1 = 0.f, o2 = 0.f, o3 = 0.f;
    float o4 = 0.f, o5 = 0.f, o6 = 0.f, o7 = 0.f;
    for (int base = beg; base < end; base += 64) {
        int idx = base + lane;
        int nv = (idx < end) ? nbr[idx] : 0;
        int m = min(64, end - base);
        int tt = 0;
        for (; tt + 16 <= m; tt += 16) {
            int n0 = __shfl(nv, tt + 0 + half);
            int n1 = __shfl(nv, tt + 2 + half);
            int n2 = __shfl(nv, tt + 4 + half);
            int n3 = __shfl(nv, tt + 6 + half);
            int n4 = __shfl(nv, tt + 8 + half);
            int n5 = __shfl(nv, tt + 10 + half);
            int n6 = __shfl(nv, tt + 12 + half);
            int n7 = __shfl(nv, tt + 14 + half);
            unsigned u0 = B2[(long)n0 * 32 + c];
            unsigned u1 = B2[(long)n1 * 32 + c];
            unsigned u2 = B2[(long)n2 * 32 + c];
            unsigned u3 = B2[(long)n3 * 32 + c];
            unsigned u4 = B2[(long)n4 * 32 + c];
            unsigned u5 = B2[(long)n5 * 32 + c];
            unsigned u6 = B2[(long)n6 * 32 + c];
            unsigned u7 = B2[(long)n7 * 32 + c];
            e0 += bflo(u0); o0 += bfhi(u0);
            e1 += bflo(u1); o1 += bfhi(u1);
            e2 += bflo(u2); o2 += bfhi(u2);
            e3 += bflo(u3); o3 += bfhi(u3);
            e4 += bflo(u4); o4 += bfhi(u4);
            e5 += bflo(u5); o5 += bfhi(u5);
            e6 += bflo(u6); o6 += bfhi(u6);
            e7 += bflo(u7); o7 += bfhi(u7);
        }
        for (; tt + 2 <= m; tt += 2) {
            int n0 = __shfl(nv, tt + half);
            unsigned u0 = B2[(long)n0 * 32 + c];
            e0 += bflo(u0); o0 += bfhi(u0);
        }
        if (tt < m) {
            int n0 = __shfl(nv, tt);
            if (half == 0) {
                unsigned u0 = B2[(long)n0 * 32 + c];
                e0 += bflo(u0); o0 += bfhi(u0);
            }
        }
    }
    float es = ((e0 + e1) + (e2 + e3)) + ((e4 + e5) + (e6 + e7));
    float os = ((o0 + o1) + (o2 + o3)) + ((o4 + o5) + (o6 + o7));
    es += __shfl(es, lane ^ 32);
    os += __shfl(os, lane ^ 32);
    if (!LAST) {
        if (half == 0) {
            int deg = end - beg;
            float inv = 1.0f / (float)max(deg, 1);
            float2* Cp = (float2*)(C + (long)i * HD + 2 * c);
            float2 cur = *Cp;
            cur.x += es * inv;
            cur.y += os * inv;
            *Cp = cur;
        }
    } else {
        // fused global-mean-pool: block covers 4 consecutive nodes (sorted batch
        // -> usually same graph); cross-wave reduce in LDS, then 64 atomics.
        __shared__ float red[4][64];
        __shared__ int gid[4];
        if (half == 0) {
            int deg = end - beg;
            float inv = 1.0f / (float)max(deg, 1);
            const float2 cur = *(const float2*)(C + (long)i * HD + 2 * c);
            red[wid][2 * c]     = cur.x + es * inv;
            red[wid][2 * c + 1] = cur.y + os * inv;
        }
        if (lane == 0) gid[wid] = batch[i];
        __syncthreads();
        if (wid == 0) {
            int g0 = gid[0], g1 = gid[1], g2 = gid[2], g3 = gid[3];
            float v0 = red[0][lane], v1 = red[1][lane];
            float v2 = red[2][lane], v3 = red[3][lane];
            if (g0 == g3) {   // sorted batch: g0==g3 implies all equal
                atomicAdd(&cb[g0 * HD + lane],
                          ((v0 + v1) + (v2 + v3)) * invc[g0]);
            } else {
                atomicAdd(&cb[g0 * HD + lane], v0 * invc[g0]);
                atomicAdd(&cb[g1 * HD + lane], v1 * invc[g1]);
                atomicAdd(&cb[g2 * HD + lane], v2 * invc[g2]);
                atomicAdd(&cb[g3 * HD + lane], v3 * invc[g3]);
            }
        }
    }
}

// ---------------- fused head, row-partitioned, LDS-staged weights ----------
// Block r owns graphs 4r..4r+3 end-to-end; intermediates stay in LDS.
// All weight matrices are staged into LDS via deep independent float4 bursts
// (16-32 outstanding loads/thread) instead of per-k scalar chains; lin2/lin3
// staging is issued BEFORE the grid barrier so HBM latency hides under the
// barrier wait. Only BN column-statistics cross blocks (device-scope atomics).
__device__ __forceinline__ void gbar(int* bar, int round) {
    __syncthreads();
    if (threadIdx.x == 0) {
        __hip_atomic_fetch_add(bar, 1, __ATOMIC_ACQ_REL, __HIP_MEMORY_SCOPE_AGENT);
        int target = round * NB_HEAD;
        while (__hip_atomic_load(bar, __ATOMIC_ACQUIRE, __HIP_MEMORY_SCOPE_AGENT) < target) {}
    }
    __syncthreads();
}

__device__ __forceinline__ float ag_load(const float* p) {
    return __hip_atomic_load(p, __ATOMIC_RELAXED, __HIP_MEMORY_SCOPE_AGENT);
}

// copy NF floats (NF % 1024 == 0) global->LDS as float4, fully unrolled:
// NF/1024 independent load+write pairs per thread.
template <int NF>
__device__ __forceinline__ void stage4(float* __restrict__ s, const float* __restrict__ g) {
    const float4* g4 = (const float4*)g;
    float4* s4 = (float4*)s;
    #pragma unroll
    for (int i = 0; i < NF / 1024; i++)
        s4[i * 256 + threadIdx.x] = g4[i * 256 + threadIdx.x];
}

__global__ __launch_bounds__(256) void k_head(
        int* bar, float* __restrict__ gstat,
        const float* __restrict__ l1w, const float* __restrict__ l1b,
        const float* __restrict__ g1, const float* __restrict__ be1,
        const float* __restrict__ l2w, const float* __restrict__ l2b,
        const float* __restrict__ g2, const float* __restrict__ be2,
        const float* __restrict__ l3w, const float* __restrict__ l3b,
        const float* __restrict__ g3, const float* __restrict__ be3,
        const float* __restrict__ w4, const float* __restrict__ b4,
        const float* __restrict__ cb, float* __restrict__ out) {
    __shared__ float WB[32768];    // 128 KB weight staging buffer
    __shared__ float A1[4][64];    // cb rows (lin1 input)
    __shared__ float A2[4][256];   // lin1 output
    __shared__ float A3[4][128];   // lin2 output
    __shared__ float M3[4][64];    // lin3 output
    __shared__ float W4[640];      // lin4 weights
    float* gs1 = gstat;            // [256] lin1 col sums
    float* gq1 = gstat + 256;      // [256]
    float* gs2 = gstat + 512;      // [128]
    float* gq2 = gstat + 640;      // [128]
    float* gs3 = gstat + 768;      // [64]
    float* gq3 = gstat + 832;      // [64]
    int t = threadIdx.x;
    int r0 = blockIdx.x * 4;       // first graph row owned by this block

    // phase 0: stage lin1_w (64 KB) into WB[16384..32768), w4, cb rows
    {
        int r = t >> 6, lane = t & 63;
        A1[r][lane] = cb[(r0 + r) * HD + lane];
    }
    if (t < 160) ((float4*)W4)[t] = ((const float4*)w4)[t];
    stage4<16384>(WB + 16384, l1w);
    __syncthreads();

    // ---- lin1: K=64 -> N=256; thread t owns column t for all 4 rows ----
    float v1[4];
    {
        float bj = l1b[t];
        v1[0] = bj; v1[1] = bj; v1[2] = bj; v1[3] = bj;
        const float* Wp = WB + 16384;
        #pragma unroll 16
        for (int k = 0; k < 64; k++) {
            float w = Wp[k * 256 + t];
            v1[0] = fmaf(A1[0][k], w, v1[0]);
            v1[1] = fmaf(A1[1][k], w, v1[1]);
            v1[2] = fmaf(A1[2][k], w, v1[2]);
            v1[3] = fmaf(A1[3][k], w, v1[3]);
        }
        float s = (v1[0] + v1[1]) + (v1[2] + v1[3]);
        float q = (v1[0] * v1[0] + v1[1] * v1[1]) + (v1[2] * v1[2] + v1[3] * v1[3]);
        atomicAdd(&gs1[t], s);
        atomicAdd(&gq1[t], q);
    }
    __syncthreads();                 // all waves done reading WB hi
    stage4<32768>(WB, l2w);          // full lin2_w; latency hides under barrier
    gbar(bar, 1);
    {
        float S = ag_load(&gs1[t]), Q = ag_load(&gq1[t]);
        float mean = S * (1.0f / NUM_GRAPHS);
        float var = Q * (1.0f / NUM_GRAPHS) - mean * mean;
        float sc = rsqrtf(fmaxf(var, 0.f) + EPS) * g1[t];
        float sh = be1[t];
        #pragma unroll
        for (int r = 0; r < 4; r++)
            A2[r][t] = tanhf((v1[r] - mean) * sc + sh);
    }
    __syncthreads();                 // A2 ready (WB ready via gbar's barrier)

    // ---- lin2: K=256 -> N=128; thread = (col j2, rowpair rq2) ----
    float v2[2];
    int j2 = t & 127, rq2 = t >> 7;
    {
        float bj = l2b[j2];
        v2[0] = bj; v2[1] = bj;
        const float* a0 = A2[2 * rq2 + 0];
        const float* a1 = A2[2 * rq2 + 1];
        #pragma unroll 16
        for (int k = 0; k < 256; k++) {
            float w = WB[k * 128 + j2];
            v2[0] = fmaf(a0[k], w, v2[0]);
            v2[1] = fmaf(a1[k], w, v2[1]);
        }
        atomicAdd(&gs2[j2], v2[0] + v2[1]);
        atomicAdd(&gq2[j2], v2[0] * v2[0] + v2[1] * v2[1]);
    }
    __syncthreads();                 // all waves done reading WB
    stage4<8192>(WB, l3w);           // lin3_w; latency hides under barrier
    gbar(bar, 2);
    {
        float S = ag_load(&gs2[j2]), Q = ag_load(&gq2[j2]);
        float mean = S * (1.0f / NUM_GRAPHS);
        float var = Q * (1.0f / NUM_GRAPHS) - mean * mean;
        float sc = rsqrtf(fmaxf(var, 0.f) + EPS) * g2[j2];
        float sh = be2[j2];
        A3[2 * rq2 + 0][j2] = tanhf((v2[0] - mean) * sc + sh);
        A3[2 * rq2 + 1][j2] = tanhf((v2[1] - mean) * sc + sh);
    }
    __syncthreads();                 // A3 ready (WB ready via gbar's barrier)

    // ---- lin3: K=128 -> N=64; thread = (col j3, row rq3) ----
    float v3;
    int j3 = t & 63, rq3 = t >> 6;
    {
        float bj = l3b[j3];
        v3 = bj;
        const float* a = A3[rq3];
        #pragma unroll 16
        for (int k = 0; k < 128; k++) {
            float w = WB[k * 64 + j3];
            v3 = fmaf(a[k], w, v3);
        }
        atomicAdd(&gs3[j3], v3);
        atomicAdd(&gq3[j3], v3 * v3);
    }
    gbar(bar, 3);
    {
        float S = ag_load(&gs3[j3]), Q = ag_load(&gq3[j3]);
        float mean = S * (1.0f / NUM_GRAPHS);
        float var = Q * (1.0f / NUM_GRAPHS) - mean * mean;
        float sc = rsqrtf(fmaxf(var, 0.f) + EPS) * g3[j3];
        float sh = be3[j3];
        M3[rq3][j3] = tanhf((v3 - mean) * sc + sh);
    }
    __syncthreads();

    // ---- lin4: 4 rows x 10 outputs, all LDS-local ----
    if (t < 40) {
        int q = t / 10, jf = t % 10;
        const float* rp = M3[q];
        float s = b4[jf];
        #pragma unroll
        for (int k = 0; k < 64; k++) s = fmaf(rp[k], W4[k * 10 + jf], s);
        out[(r0 + q) * 10 + jf] = s;
    }
}

extern "C" void kernel_launch(void* const* d_in, const int* in_sizes, int n_in,
                              void* d_out, int out_size, void* d_ws, size_t ws_size,
                              hipStream_t stream) {
    const float* x     = (const float*)d_in[0];
    const int*   ei    = (const int*) d_in[1];
    const int*   batch = (const int*) d_in[2];
    const float *W1l = (const float*)d_in[3],  *b1l = (const float*)d_in[4],  *W1r = (const float*)d_in[5];
    const float *W2l = (const float*)d_in[6],  *b2l = (const float*)d_in[7],  *W2r = (const float*)d_in[8];
    const float *W3l = (const float*)d_in[9],  *b3l = (const float*)d_in[10], *W3r = (const float*)d_in[11];
    const float *lin1_w = (const float*)d_in[12], *lin1_b = (const float*)d_in[13];
    const float *g1 = (const float*)d_in[14], *be1 = (const float*)d_in[15];
    const float *lin2_w = (const float*)d_in[16], *lin2_b = (const float*)d_in[17];
    const float *g2 = (const float*)d_in[18], *be2 = (const float*)d_in[19];
    const float *lin3_w = (const float*)d_in[20], *lin3_b = (const float*)d_in[21];
    const float *g3 = (const float*)d_in[22], *be3 = (const float*)d_in[23];
    const float *lin4_w = (const float*)d_in[24], *lin4_b = (const float*)d_in[25];

    const int* srcp = ei;
    const int* dstp = ei + N_EDGES;

    // ---- workspace layout ----
    const long NF = (long)N_NODES * HD;              // 3,200,000
    char* wsb  = (char*)d_ws;
    int*  cnti = (int*)wsb;                          // 50,048
    int*  bar  = cnti + 50048;                       // 8
    float* gstat = (float*)(bar + 8);                // 896 (zeroed with cnti)
    int*  pos  = (int*)(gstat + 896);                // 800,000
    int*  off  = pos  + 800000;                      // 50,056
    int*  nbr  = off  + 50056;                       // 800,000
    int*  bsum = nbr  + 800000;                      // 256
    int*  gb   = bsum + 256;                         // 264 (257 used)
    float* invc = (float*)(gb + 264);                // 256
    bf16* B    = (bf16*)(invc + 256);                // 3,200,000 bf16
    float* H1  = (float*)(B + NF);                   // 3,200,000
    float* H2  = H1  + NF;                           // 3,200,000
    float* cb  = H2  + NF;                           // 16,384
    float* endp= cb  + NUM_GRAPHS * HD;

    const size_t NEED = (size_t)((char*)endp - wsb);
    if (ws_size < NEED) {
        k_diag<<<(out_size + 255) / 256, 256, 0, stream>>>((float*)d_out, out_size,
                                                           (float)(ws_size >> 20));
        return;
    }

    const int TB = 256;
    const int gNE = (N_EDGES + TB - 1) / TB;
    const int gNF = (int)((NF + TB - 1) / TB);        // 12500 (= exactly 50000 nodes)
    const int gXB = (N_NODES + 31) / 32;              // 1563

    hipMemsetAsync(cnti, 0, (50048 + 8 + 896) * sizeof(int), stream);
    hipMemsetAsync(cb, 0, NUM_GRAPHS * HD * sizeof(float), stream);

    // ---- CSR build (+ graph bounds) ----
    k_count<<<gNE, TB, 0, stream>>>(dstp, batch, cnti, pos, gb);
    k_scan1<<<SCAN_NB, TB, 0, stream>>>(cnti, off, bsum);
    k_scan3<<<SCAN_NB, TB, 0, stream>>>(off, bsum, gb, invc);
    k_fill<<<gNE, TB, 0, stream>>>(srcp, dstp, off, pos, nbr);

    // ---- SAGE layers (bf16 messages, pairwise gather) ----
    k_xform3<IN_DIM><<<gXB, TB, 0, stream>>>(x, W1l, W1r, b1l, B, H1);
    k_gather<false><<<gNF, TB, 0, stream>>>(off, nbr, B, H1, batch, invc, cb);
    k_xform3<HD><<<gXB, TB, 0, stream>>>(H1, W2l, W2r, b2l, B, H2);
    k_gather<false><<<gNF, TB, 0, stream>>>(off, nbr, B, H2, batch, invc, cb);
    k_xform3<HD><<<gXB, TB, 0, stream>>>(H2, W3l, W3r, b3l, B, H1);
    // last gather: fused global-mean-pool into cb (H1 never written back)
    k_gather<true><<<gNF, TB, 0, stream>>>(off, nbr, B, H1, batch, invc, cb);

    // ---- fused head: row-partitioned, LDS-staged weights ----
    k_head<<<NB_HEAD, TB, 0, stream>>>(bar, gstat,
                                       lin1_w, lin1_b, g1, be1,
                                       lin2_w, lin2_b, g2, be2,
                                       lin3_w, lin3_b, g3, be3,
                                       lin4_w, lin4_b,
                                       cb, (float*)d_out);
}

// Round 5
// 376.193 us; speedup vs baseline: 1.2451x; 1.0082x over previous
//
#include <hip/hip_runtime.h>
#include <hip/hip_bf16.h>

#define N_NODES   50000
#define N_EDGES   800000
#define NUM_GRAPHS 256
#define IN_DIM    128
#define HD        64
#define EPS       1e-5f
#define SCAN_NB   196      // ceil(50000/256)
#define NB_HEAD   64       // head kernel grid (must be <= CU count for co-residency)

typedef __hip_bfloat16 bf16;

// ---------------- diagnostics ----------------
__global__ void k_diag(float* __restrict__ out, int n, float v) {
    int t = blockIdx.x * 256 + threadIdx.x;
    if (t < n) out[t] = v;
}

// ---------------- CSR build (+ graph bounds for pooling) ----------------
__global__ void k_count(const int* __restrict__ dst, const int* __restrict__ batch,
                        int* __restrict__ cnti, int* __restrict__ pos,
                        int* __restrict__ gb) {
    int e = blockIdx.x * 256 + threadIdx.x;
    if (e < N_EDGES) pos[e] = atomicAdd(&cnti[dst[e]], 1);
    // graph bounds: gb[g] = first node index with batch >= g (batch is sorted)
    if (e < N_NODES) {
        int bg = batch[e];
        int bnext = (e + 1 < N_NODES) ? batch[e + 1] : NUM_GRAPHS;
        if (e == 0) {
            for (int g = 0; g <= bg; ++g) gb[g] = 0;
        }
        for (int g = bg + 1; g <= bnext; ++g) gb[g] = e + 1;
    }
}

__global__ void k_scan1(const int* __restrict__ cnti, int* __restrict__ off,
                        int* __restrict__ bsum) {
    __shared__ int wsum[4];
    int idx = blockIdx.x * 256 + threadIdx.x;
    int lane = threadIdx.x & 63, wid = threadIdx.x >> 6;
    int v = (idx < N_NODES) ? cnti[idx] : 0;
    int s = v;
    #pragma unroll
    for (int o = 1; o < 64; o <<= 1) {
        int u = __shfl_up(s, o);
        if (lane >= o) s += u;
    }
    if (lane == 63) wsum[wid] = s;
    __syncthreads();
    int wbase = 0;
    #pragma unroll
    for (int w = 0; w < 4; w++) wbase += (w < wid) ? wsum[w] : 0;
    if (idx < N_NODES) off[idx] = wbase + s - v;
    if (threadIdx.x == 255) bsum[blockIdx.x] = wbase + s;
}

__global__ void k_scan3(int* __restrict__ off, const int* __restrict__ bsum,
                        const int* __restrict__ gb, float* __restrict__ invc) {
    __shared__ int wsum[4];
    __shared__ int spre;
    int lane = threadIdx.x & 63, wid = threadIdx.x >> 6;
    int v = (threadIdx.x < blockIdx.x) ? bsum[threadIdx.x] : 0;
    #pragma unroll
    for (int o = 32; o > 0; o >>= 1) v += __shfl_down(v, o);
    if (lane == 0) wsum[wid] = v;
    __syncthreads();
    if (threadIdx.x == 0) spre = wsum[0] + wsum[1] + wsum[2] + wsum[3];
    __syncthreads();
    int pre = spre;
    int idx = blockIdx.x * 256 + threadIdx.x;
    if (idx < N_NODES) off[idx] += pre;
    else if (idx == N_NODES) off[N_NODES] = N_EDGES;
    // per-graph 1/count for fused pooling (gb ready since k_count)
    if (blockIdx.x == 0 && threadIdx.x < NUM_GRAPHS) {
        int c0 = gb[threadIdx.x], c1 = gb[threadIdx.x + 1];
        invc[threadIdx.x] = 1.0f / (float)max(c1 - c0, 1);
    }
}

__global__ void k_fill(const int* __restrict__ src, const int* __restrict__ dst,
                       const int* __restrict__ off, const int* __restrict__ pos,
                       int* __restrict__ nbr) {
    int e = blockIdx.x * 256 + threadIdx.x;
    if (e >= N_EDGES) return;
    int d = dst[e];
    nbr[off[d] + pos[e]] = src[e];
}

// ---- fused transform, LDS-staged X tile + LDS-staged weights ----
// B(bf16) = X@Wl ; C = X@Wr + bl. Weights read from LDS (stride-1,
// conflict-free); X tile reads are wave-uniform broadcasts.
template <int K>
__global__ __launch_bounds__(256) void k_xform3(
        const float* __restrict__ X, const float* __restrict__ Wl,
        const float* __restrict__ Wr, const float* __restrict__ bl,
        bf16* __restrict__ B, float* __restrict__ C) {
    __shared__ float tile[32 * K];
    __shared__ float WsL[K * HD];
    __shared__ float WsR[K * HD];
    const int NPW = 8;
    int nodes0 = blockIdx.x * 32;
    {
        const int total4 = 32 * K / 4;
        int nmax4 = (N_NODES - nodes0) * K / 4;
        const float4* Xg = (const float4*)(X + (long)nodes0 * K);
        float4* tg = (float4*)tile;
        for (int idx = threadIdx.x; idx < total4; idx += 256) {
            float4 v = make_float4(0.f, 0.f, 0.f, 0.f);
            if (idx < nmax4) v = Xg[idx];
            tg[idx] = v;
        }
    }
    {
        const int W4N = K * HD / 4;          // 2048 (K=128) / 1024 (K=64)
        const float4* gl = (const float4*)Wl;
        const float4* gr = (const float4*)Wr;
        float4* sl = (float4*)WsL;
        float4* sr = (float4*)WsR;
        #pragma unroll
        for (int idx = threadIdx.x; idx < W4N; idx += 256) {
            sl[idx] = gl[idx];
            sr[idx] = gr[idx];
        }
    }
    __syncthreads();
    int wave = threadIdx.x >> 6, j = threadIdx.x & 63;
    long base = (long)nodes0 + wave * NPW;
    if (base >= N_NODES) return;
    float accB[NPW], accC[NPW];
    #pragma unroll
    for (int n = 0; n < NPW; n++) { accB[n] = 0.f; accC[n] = 0.f; }
    const float* Xs = tile + (wave * NPW) * K;
    for (int kc = 0; kc < K; kc += 4) {
        float wl0 = WsL[(kc + 0) * HD + j], wr0 = WsR[(kc + 0) * HD + j];
        float wl1 = WsL[(kc + 1) * HD + j], wr1 = WsR[(kc + 1) * HD + j];
        float wl2 = WsL[(kc + 2) * HD + j], wr2 = WsR[(kc + 2) * HD + j];
        float wl3 = WsL[(kc + 3) * HD + j], wr3 = WsR[(kc + 3) * HD + j];
        #pragma unroll
        for (int n = 0; n < NPW; n++) {
            float4 xv = *(const float4*)(Xs + n * K + kc);
            accB[n] = fmaf(xv.x, wl0, accB[n]);
            accC[n] = fmaf(xv.x, wr0, accC[n]);
            accB[n] = fmaf(xv.y, wl1, accB[n]);
            accC[n] = fmaf(xv.y, wr1, accC[n]);
            accB[n] = fmaf(xv.z, wl2, accB[n]);
            accC[n] = fmaf(xv.z, wr2, accC[n]);
            accB[n] = fmaf(xv.w, wl3, accB[n]);
            accC[n] = fmaf(xv.w, wr3, accC[n]);
        }
    }
    float bb = bl[j];
    int nact = (int)min((long)NPW, (long)N_NODES - base);
    for (int n = 0; n < nact; n++) {
        long i = base + n;
        B[i * HD + j] = __float2bfloat16(accB[n]);
        C[i * HD + j] = accC[n] + bb;
    }
}

__device__ __forceinline__ float bflo(unsigned u) { return __uint_as_float(u << 16); }
__device__ __forceinline__ float bfhi(unsigned u) { return __uint_as_float(u & 0xffff0000u); }

// ---- CSR gather, quad-row (4 neighbor rows per wave-load, uint2/lane) ----
// 16 lanes x 8 B cover one 128 B row; quarter q = lane>>4 owns row slot q.
// LAST=true: fuse the global mean pool: accumulate (C_row + mean_aggr) *
// invc[batch[i]] into cb via device-scope atomics.
template <bool LAST>
__global__ void k_gather(const int* __restrict__ off, const int* __restrict__ nbr,
                         const bf16* __restrict__ Bm, float* __restrict__ C,
                         const int* __restrict__ batch, const float* __restrict__ invc,
                         float* __restrict__ cb) {
    int t = blockIdx.x * 256 + threadIdx.x;
    int i = t >> 6, lane = t & 63;
    if (!LAST && i >= N_NODES) return;
    int q = lane >> 4, c2 = lane & 15;
    int wid = threadIdx.x >> 6;
    const uint2* B2 = (const uint2*)Bm;       // 16 uint2 per 64-col bf16 row
    int beg = off[i], end = off[i + 1];
    float4 a0 = make_float4(0.f, 0.f, 0.f, 0.f);
    float4 a1 = make_float4(0.f, 0.f, 0.f, 0.f);
    float4 a2 = make_float4(0.f, 0.f, 0.f, 0.f);
    float4 a3 = make_float4(0.f, 0.f, 0.f, 0.f);
    for (int base = beg; base < end; base += 64) {
        int idx = base + lane;
        int nv = (idx < end) ? nbr[idx] : 0;
        int m = min(64, end - base);
        int tt = 0;
        for (; tt + 16 <= m; tt += 16) {
            int n0 = __shfl(nv, tt + 0 + q);
            int n1 = __shfl(nv, tt + 4 + q);
            int n2 = __shfl(nv, tt + 8 + q);
            int n3 = __shfl(nv, tt + 12 + q);
            uint2 u0 = B2[(long)n0 * 16 + c2];
            uint2 u1 = B2[(long)n1 * 16 + c2];
            uint2 u2 = B2[(long)n2 * 16 + c2];
            uint2 u3 = B2[(long)n3 * 16 + c2];
            a0.x += bflo(u0.x); a0.y += bfhi(u0.x); a0.z += bflo(u0.y); a0.w += bfhi(u0.y);
            a1.x += bflo(u1.x); a1.y += bfhi(u1.x); a1.z += bflo(u1.y); a1.w += bfhi(u1.y);
            a2.x += bflo(u2.x); a2.y += bfhi(u2.x); a2.z += bflo(u2.y); a2.w += bfhi(u2.y);
            a3.x += bflo(u3.x); a3.y += bfhi(u3.x); a3.z += bflo(u3.y); a3.w += bfhi(u3.y);
        }
        for (; tt < m; tt += 4) {
            int n0 = __shfl(nv, tt + q);
            if (tt + q < m) {
                uint2 u0 = B2[(long)n0 * 16 + c2];
                a0.x += bflo(u0.x); a0.y += bfhi(u0.x);
                a0.z += bflo(u0.y); a0.w += bfhi(u0.y);
            }
        }
    }
    float4 s;
    s.x = (a0.x + a1.x) + (a2.x + a3.x);
    s.y = (a0.y + a1.y) + (a2.y + a3.y);
    s.z = (a0.z + a1.z) + (a2.z + a3.z);
    s.w = (a0.w + a1.w) + (a2.w + a3.w);
    s.x += __shfl_xor(s.x, 16); s.x += __shfl_xor(s.x, 32);
    s.y += __shfl_xor(s.y, 16); s.y += __shfl_xor(s.y, 32);
    s.z += __shfl_xor(s.z, 16); s.z += __shfl_xor(s.z, 32);
    s.w += __shfl_xor(s.w, 16); s.w += __shfl_xor(s.w, 32);
    if (!LAST) {
        if (lane < 16) {
            int deg = end - beg;
            float inv = 1.0f / (float)max(deg, 1);
            float4* Cp = (float4*)(C + (long)i * HD + 4 * lane);
            float4 cur = *Cp;
            cur.x += s.x * inv;
            cur.y += s.y * inv;
            cur.z += s.z * inv;
            cur.w += s.w * inv;
            *Cp = cur;
        }
    } else {
        // fused global-mean-pool: block covers 4 consecutive nodes (sorted batch
        // -> usually same graph); cross-wave reduce in LDS, then 64 atomics.
        __shared__ float red[4][64];
        __shared__ int gid[4];
        if (lane < 16) {
            int deg = end - beg;
            float inv = 1.0f / (float)max(deg, 1);
            const float4 cur = *(const float4*)(C + (long)i * HD + 4 * lane);
            red[wid][4 * lane + 0] = cur.x + s.x * inv;
            red[wid][4 * lane + 1] = cur.y + s.y * inv;
            red[wid][4 * lane + 2] = cur.z + s.z * inv;
            red[wid][4 * lane + 3] = cur.w + s.w * inv;
        }
        if (lane == 0) gid[wid] = batch[i];
        __syncthreads();
        if (wid == 0) {
            int g0 = gid[0], g1 = gid[1], g2 = gid[2], g3 = gid[3];
            float v0 = red[0][lane], v1 = red[1][lane];
            float v2 = red[2][lane], v3 = red[3][lane];
            if (g0 == g3) {   // sorted batch: g0==g3 implies all equal
                atomicAdd(&cb[g0 * HD + lane],
                          ((v0 + v1) + (v2 + v3)) * invc[g0]);
            } else {
                atomicAdd(&cb[g0 * HD + lane], v0 * invc[g0]);
                atomicAdd(&cb[g1 * HD + lane], v1 * invc[g1]);
                atomicAdd(&cb[g2 * HD + lane], v2 * invc[g2]);
                atomicAdd(&cb[g3 * HD + lane], v3 * invc[g3]);
            }
        }
    }
}

// ---------------- fused head, row-partitioned, LDS-staged weights ----------
// Block r owns graphs 4r..4r+3 end-to-end; intermediates stay in LDS.
// All weight matrices are staged into LDS via deep independent float4 bursts;
// lin2/lin3 staging is issued BEFORE the grid barrier so HBM latency hides
// under the barrier wait. Only BN column-statistics cross blocks.
__device__ __forceinline__ void gbar(int* bar, int round) {
    __syncthreads();
    if (threadIdx.x == 0) {
        __hip_atomic_fetch_add(bar, 1, __ATOMIC_ACQ_REL, __HIP_MEMORY_SCOPE_AGENT);
        int target = round * NB_HEAD;
        while (__hip_atomic_load(bar, __ATOMIC_ACQUIRE, __HIP_MEMORY_SCOPE_AGENT) < target) {}
    }
    __syncthreads();
}

__device__ __forceinline__ float ag_load(const float* p) {
    return __hip_atomic_load(p, __ATOMIC_RELAXED, __HIP_MEMORY_SCOPE_AGENT);
}

// copy NF floats (NF % 1024 == 0) global->LDS as float4, fully unrolled
template <int NF>
__device__ __forceinline__ void stage4(float* __restrict__ s, const float* __restrict__ g) {
    const float4* g4 = (const float4*)g;
    float4* s4 = (float4*)s;
    #pragma unroll
    for (int i = 0; i < NF / 1024; i++)
        s4[i * 256 + threadIdx.x] = g4[i * 256 + threadIdx.x];
}

__global__ __launch_bounds__(256) void k_head(
        int* bar, float* __restrict__ gstat,
        const float* __restrict__ l1w, const float* __restrict__ l1b,
        const float* __restrict__ g1, const float* __restrict__ be1,
        const float* __restrict__ l2w, const float* __restrict__ l2b,
        const float* __restrict__ g2, const float* __restrict__ be2,
        const float* __restrict__ l3w, const float* __restrict__ l3b,
        const float* __restrict__ g3, const float* __restrict__ be3,
        const float* __restrict__ w4, const float* __restrict__ b4,
        const float* __restrict__ cb, float* __restrict__ out) {
    __shared__ float WB[32768];    // 128 KB weight staging buffer
    __shared__ float A1[4][64];    // cb rows (lin1 input)
    __shared__ float A2[4][256];   // lin1 output
    __shared__ float A3[4][128];   // lin2 output
    __shared__ float M3[4][64];    // lin3 output
    __shared__ float W4[640];      // lin4 weights
    float* gs1 = gstat;            // [256] lin1 col sums
    float* gq1 = gstat + 256;      // [256]
    float* gs2 = gstat + 512;      // [128]
    float* gq2 = gstat + 640;      // [128]
    float* gs3 = gstat + 768;      // [64]
    float* gq3 = gstat + 832;      // [64]
    int t = threadIdx.x;
    int r0 = blockIdx.x * 4;       // first graph row owned by this block

    // phase 0: stage lin1_w (64 KB) into WB[16384..32768), w4, cb rows
    {
        int r = t >> 6, lane = t & 63;
        A1[r][lane] = cb[(r0 + r) * HD + lane];
    }
    if (t < 160) ((float4*)W4)[t] = ((const float4*)w4)[t];
    stage4<16384>(WB + 16384, l1w);
    __syncthreads();

    // ---- lin1: K=64 -> N=256; thread t owns column t for all 4 rows ----
    float v1[4];
    {
        float bj = l1b[t];
        v1[0] = bj; v1[1] = bj; v1[2] = bj; v1[3] = bj;
        const float* Wp = WB + 16384;
        #pragma unroll 16
        for (int k = 0; k < 64; k++) {
            float w = Wp[k * 256 + t];
            v1[0] = fmaf(A1[0][k], w, v1[0]);
            v1[1] = fmaf(A1[1][k], w, v1[1]);
            v1[2] = fmaf(A1[2][k], w, v1[2]);
            v1[3] = fmaf(A1[3][k], w, v1[3]);
        }
        float s = (v1[0] + v1[1]) + (v1[2] + v1[3]);
        float q = (v1[0] * v1[0] + v1[1] * v1[1]) + (v1[2] * v1[2] + v1[3] * v1[3]);
        atomicAdd(&gs1[t], s);
        atomicAdd(&gq1[t], q);
    }
    __syncthreads();                 // all waves done reading WB hi
    stage4<32768>(WB, l2w);          // full lin2_w; latency hides under barrier
    gbar(bar, 1);
    {
        float S = ag_load(&gs1[t]), Q = ag_load(&gq1[t]);
        float mean = S * (1.0f / NUM_GRAPHS);
        float var = Q * (1.0f / NUM_GRAPHS) - mean * mean;
        float sc = rsqrtf(fmaxf(var, 0.f) + EPS) * g1[t];
        float sh = be1[t];
        #pragma unroll
        for (int r = 0; r < 4; r++)
            A2[r][t] = tanhf((v1[r] - mean) * sc + sh);
    }
    __syncthreads();                 // A2 ready (WB ready via gbar's barrier)

    // ---- lin2: K=256 -> N=128; thread = (col j2, rowpair rq2) ----
    float v2[2];
    int j2 = t & 127, rq2 = t >> 7;
    {
        float bj = l2b[j2];
        v2[0] = bj; v2[1] = bj;
        const float* a0 = A2[2 * rq2 + 0];
        const float* a1 = A2[2 * rq2 + 1];
        #pragma unroll 16
        for (int k = 0; k < 256; k++) {
            float w = WB[k * 128 + j2];
            v2[0] = fmaf(a0[k], w, v2[0]);
            v2[1] = fmaf(a1[k], w, v2[1]);
        }
        atomicAdd(&gs2[j2], v2[0] + v2[1]);
        atomicAdd(&gq2[j2], v2[0] * v2[0] + v2[1] * v2[1]);
    }
    __syncthreads();                 // all waves done reading WB
    stage4<8192>(WB, l3w);           // lin3_w; latency hides under barrier
    gbar(bar, 2);
    {
        float S = ag_load(&gs2[j2]), Q = ag_load(&gq2[j2]);
        float mean = S * (1.0f / NUM_GRAPHS);
        float var = Q * (1.0f / NUM_GRAPHS) - mean * mean;
        float sc = rsqrtf(fmaxf(var, 0.f) + EPS) * g2[j2];
        float sh = be2[j2];
        A3[2 * rq2 + 0][j2] = tanhf((v2[0] - mean) * sc + sh);
        A3[2 * rq2 + 1][j2] = tanhf((v2[1] - mean) * sc + sh);
    }
    __syncthreads();                 // A3 ready (WB ready via gbar's barrier)

    // ---- lin3: K=128 -> N=64; thread = (col j3, row rq3) ----
    float v3;
    int j3 = t & 63, rq3 = t >> 6;
    {
        float bj = l3b[j3];
        v3 = bj;
        const float* a = A3[rq3];
        #pragma unroll 16
        for (int k = 0; k < 128; k++) {
            float w = WB[k * 64 + j3];
            v3 = fmaf(a[k], w, v3);
        }
        atomicAdd(&gs3[j3], v3);
        atomicAdd(&gq3[j3], v3 * v3);
    }
    gbar(bar, 3);
    {
        float S = ag_load(&gs3[j3]), Q = ag_load(&gq3[j3]);
        float mean = S * (1.0f / NUM_GRAPHS);
        float var = Q * (1.0f / NUM_GRAPHS) - mean * mean;
        float sc = rsqrtf(fmaxf(var, 0.f) + EPS) * g3[j3];
        float sh = be3[j3];
        M3[rq3][j3] = tanhf((v3 - mean) * sc + sh);
    }
    __syncthreads();

    // ---- lin4: 4 rows x 10 outputs, all LDS-local ----
    if (t < 40) {
        int q = t / 10, jf = t % 10;
        const float* rp = M3[q];
        float s = b4[jf];
        #pragma unroll
        for (int k = 0; k < 64; k++) s = fmaf(rp[k], W4[k * 10 + jf], s);
        out[(r0 + q) * 10 + jf] = s;
    }
}

extern "C" void kernel_launch(void* const* d_in, const int* in_sizes, int n_in,
                              void* d_out, int out_size, void* d_ws, size_t ws_size,
                              hipStream_t stream) {
    const float* x     = (const float*)d_in[0];
    const int*   ei    = (const int*) d_in[1];
    const int*   batch = (const int*) d_in[2];
    const float *W1l = (const float*)d_in[3],  *b1l = (const float*)d_in[4],  *W1r = (const float*)d_in[5];
    const float *W2l = (const float*)d_in[6],  *b2l = (const float*)d_in[7],  *W2r = (const float*)d_in[8];
    const float *W3l = (const float*)d_in[9],  *b3l = (const float*)d_in[10], *W3r = (const float*)d_in[11];
    const float *lin1_w = (const float*)d_in[12], *lin1_b = (const float*)d_in[13];
    const float *g1 = (const float*)d_in[14], *be1 = (const float*)d_in[15];
    const float *lin2_w = (const float*)d_in[16], *lin2_b = (const float*)d_in[17];
    const float *g2 = (const float*)d_in[18], *be2 = (const float*)d_in[19];
    const float *lin3_w = (const float*)d_in[20], *lin3_b = (const float*)d_in[21];
    const float *g3 = (const float*)d_in[22], *be3 = (const float*)d_in[23];
    const float *lin4_w = (const float*)d_in[24], *lin4_b = (const float*)d_in[25];

    const int* srcp = ei;
    const int* dstp = ei + N_EDGES;

    // ---- workspace layout ----
    const long NF = (long)N_NODES * HD;              // 3,200,000
    char* wsb  = (char*)d_ws;
    int*  cnti = (int*)wsb;                          // 50,048
    int*  bar  = cnti + 50048;                       // 8
    float* gstat = (float*)(bar + 8);                // 896 (zeroed with cnti)
    int*  pos  = (int*)(gstat + 896);                // 800,000
    int*  off  = pos  + 800000;                      // 50,056
    int*  nbr  = off  + 50056;                       // 800,000
    int*  bsum = nbr  + 800000;                      // 256
    int*  gb   = bsum + 256;                         // 264 (257 used)
    float* invc = (float*)(gb + 264);                // 256
    bf16* B    = (bf16*)(invc + 256);                // 3,200,000 bf16
    float* H1  = (float*)(B + NF);                   // 3,200,000
    float* H2  = H1  + NF;                           // 3,200,000
    float* cb  = H2  + NF;                           // 16,384
    float* endp= cb  + NUM_GRAPHS * HD;

    const size_t NEED = (size_t)((char*)endp - wsb);
    if (ws_size < NEED) {
        k_diag<<<(out_size + 255) / 256, 256, 0, stream>>>((float*)d_out, out_size,
                                                           (float)(ws_size >> 20));
        return;
    }

    const int TB = 256;
    const int gNE = (N_EDGES + TB - 1) / TB;
    const int gNF = (int)((NF + TB - 1) / TB);        // 12500 (= exactly 50000 nodes)
    const int gXB = (N_NODES + 31) / 32;              // 1563

    hipMemsetAsync(cnti, 0, (50048 + 8 + 896) * sizeof(int), stream);
    hipMemsetAsync(cb, 0, NUM_GRAPHS * HD * sizeof(float), stream);

    // ---- CSR build (+ graph bounds) ----
    k_count<<<gNE, TB, 0, stream>>>(dstp, batch, cnti, pos, gb);
    k_scan1<<<SCAN_NB, TB, 0, stream>>>(cnti, off, bsum);
    k_scan3<<<SCAN_NB, TB, 0, stream>>>(off, bsum, gb, invc);
    k_fill<<<gNE, TB, 0, stream>>>(srcp, dstp, off, pos, nbr);

    // ---- SAGE layers (bf16 messages, quad-row gather) ----
    k_xform3<IN_DIM><<<gXB, TB, 0, stream>>>(x, W1l, W1r, b1l, B, H1);
    k_gather<false><<<gNF, TB, 0, stream>>>(off, nbr, B, H1, batch, invc, cb);
    k_xform3<HD><<<gXB, TB, 0, stream>>>(H1, W2l, W2r, b2l, B, H2);
    k_gather<false><<<gNF, TB, 0, stream>>>(off, nbr, B, H2, batch, invc, cb);
    k_xform3<HD><<<gXB, TB, 0, stream>>>(H2, W3l, W3r, b3l, B, H1);
    // last gather: fused global-mean-pool into cb (H1 never written back)
    k_gather<true><<<gNF, TB, 0, stream>>>(off, nbr, B, H1, batch, invc, cb);

    // ---- fused head: row-partitioned, LDS-staged weights ----
    k_head<<<NB_HEAD, TB, 0, stream>>>(bar, gstat,
                                       lin1_w, lin1_b, g1, be1,
                                       lin2_w, lin2_b, g2, be2,
                                       lin3_w, lin3_b, g3, be3,
                                       lin4_w, lin4_b,
                                       cb, (float*)d_out);
}

// Round 6
// 375.117 us; speedup vs baseline: 1.2487x; 1.0029x over previous
//
#include <hip/hip_runtime.h>
#include <hip/hip_bf16.h>

#define N_NODES   50000
#define N_EDGES   800000
#define NUM_GRAPHS 256
#define IN_DIM    128
#define HD        64
#define EPS       1e-5f
#define SCAN_NB   196      // ceil(50000/256)
#define NB_HEAD   64       // head kernel grid (must be <= CU count for co-residency)

typedef __hip_bfloat16 bf16;

// ---------------- diagnostics ----------------
__global__ void k_diag(float* __restrict__ out, int n, float v) {
    int t = blockIdx.x * 256 + threadIdx.x;
    if (t < n) out[t] = v;
}

// ---------------- CSR build (+ graph bounds for pooling) ----------------
__global__ void k_count(const int* __restrict__ dst, const int* __restrict__ batch,
                        int* __restrict__ cnti, int* __restrict__ pos,
                        int* __restrict__ gb) {
    int e = blockIdx.x * 256 + threadIdx.x;
    if (e < N_EDGES) pos[e] = atomicAdd(&cnti[dst[e]], 1);
    // graph bounds: gb[g] = first node index with batch >= g (batch is sorted)
    if (e < N_NODES) {
        int bg = batch[e];
        int bnext = (e + 1 < N_NODES) ? batch[e + 1] : NUM_GRAPHS;
        if (e == 0) {
            for (int g = 0; g <= bg; ++g) gb[g] = 0;
        }
        for (int g = bg + 1; g <= bnext; ++g) gb[g] = e + 1;
    }
}

__global__ void k_scan1(const int* __restrict__ cnti, int* __restrict__ off,
                        int* __restrict__ bsum) {
    __shared__ int wsum[4];
    int idx = blockIdx.x * 256 + threadIdx.x;
    int lane = threadIdx.x & 63, wid = threadIdx.x >> 6;
    int v = (idx < N_NODES) ? cnti[idx] : 0;
    int s = v;
    #pragma unroll
    for (int o = 1; o < 64; o <<= 1) {
        int u = __shfl_up(s, o);
        if (lane >= o) s += u;
    }
    if (lane == 63) wsum[wid] = s;
    __syncthreads();
    int wbase = 0;
    #pragma unroll
    for (int w = 0; w < 4; w++) wbase += (w < wid) ? wsum[w] : 0;
    if (idx < N_NODES) off[idx] = wbase + s - v;
    if (threadIdx.x == 255) bsum[blockIdx.x] = wbase + s;
}

__global__ void k_scan3(int* __restrict__ off, const int* __restrict__ bsum,
                        const int* __restrict__ gb, float* __restrict__ invc) {
    __shared__ int wsum[4];
    __shared__ int spre;
    int lane = threadIdx.x & 63, wid = threadIdx.x >> 6;
    int v = (threadIdx.x < blockIdx.x) ? bsum[threadIdx.x] : 0;
    #pragma unroll
    for (int o = 32; o > 0; o >>= 1) v += __shfl_down(v, o);
    if (lane == 0) wsum[wid] = v;
    __syncthreads();
    if (threadIdx.x == 0) spre = wsum[0] + wsum[1] + wsum[2] + wsum[3];
    __syncthreads();
    int pre = spre;
    int idx = blockIdx.x * 256 + threadIdx.x;
    if (idx < N_NODES) off[idx] += pre;
    else if (idx == N_NODES) off[N_NODES] = N_EDGES;
    // per-graph 1/count for fused pooling (gb ready since k_count)
    if (blockIdx.x == 0 && threadIdx.x < NUM_GRAPHS) {
        int c0 = gb[threadIdx.x], c1 = gb[threadIdx.x + 1];
        invc[threadIdx.x] = 1.0f / (float)max(c1 - c0, 1);
    }
}

__global__ void k_fill(const int* __restrict__ src, const int* __restrict__ dst,
                       const int* __restrict__ off, const int* __restrict__ pos,
                       int* __restrict__ nbr) {
    int e = blockIdx.x * 256 + threadIdx.x;
    if (e >= N_EDGES) return;
    int d = dst[e];
    nbr[off[d] + pos[e]] = src[e];
}

// ---- fused transform, LDS-staged X tile (64 nodes/block, 16 nodes/wave) ----
// B(bf16) = X@Wl ; C = X@Wr + bl. Weights via global loads (L2-broadcast);
// per-wave FMA:load ratio doubled vs 8-node tile to hide L2 latency.
template <int K>
__global__ __launch_bounds__(256) void k_xform3(
        const float* __restrict__ X, const float* __restrict__ Wl,
        const float* __restrict__ Wr, const float* __restrict__ bl,
        bf16* __restrict__ B, float* __restrict__ C) {
    __shared__ float tile[64 * K];
    const int NPW = 16;
    int nodes0 = blockIdx.x * 64;
    {
        const int total4 = 64 * K / 4;
        int nmax4 = (N_NODES - nodes0) * K / 4;
        const float4* Xg = (const float4*)(X + (long)nodes0 * K);
        float4* tg = (float4*)tile;
        for (int idx = threadIdx.x; idx < total4; idx += 256) {
            float4 v = make_float4(0.f, 0.f, 0.f, 0.f);
            if (idx < nmax4) v = Xg[idx];
            tg[idx] = v;
        }
    }
    __syncthreads();
    int wave = threadIdx.x >> 6, j = threadIdx.x & 63;
    long base = (long)nodes0 + wave * NPW;
    if (base >= N_NODES) return;
    float accB[NPW], accC[NPW];
    #pragma unroll
    for (int n = 0; n < NPW; n++) { accB[n] = 0.f; accC[n] = 0.f; }
    const float* Xs = tile + (wave * NPW) * K;
    for (int kc = 0; kc < K; kc += 4) {
        float wl0 = Wl[(kc + 0) * HD + j], wr0 = Wr[(kc + 0) * HD + j];
        float wl1 = Wl[(kc + 1) * HD + j], wr1 = Wr[(kc + 1) * HD + j];
        float wl2 = Wl[(kc + 2) * HD + j], wr2 = Wr[(kc + 2) * HD + j];
        float wl3 = Wl[(kc + 3) * HD + j], wr3 = Wr[(kc + 3) * HD + j];
        #pragma unroll
        for (int n = 0; n < NPW; n++) {
            float4 xv = *(const float4*)(Xs + n * K + kc);
            accB[n] = fmaf(xv.x, wl0, accB[n]);
            accC[n] = fmaf(xv.x, wr0, accC[n]);
            accB[n] = fmaf(xv.y, wl1, accB[n]);
            accC[n] = fmaf(xv.y, wr1, accC[n]);
            accB[n] = fmaf(xv.z, wl2, accB[n]);
            accC[n] = fmaf(xv.z, wr2, accC[n]);
            accB[n] = fmaf(xv.w, wl3, accB[n]);
            accC[n] = fmaf(xv.w, wr3, accC[n]);
        }
    }
    float bb = bl[j];
    int nact = (int)min((long)NPW, (long)N_NODES - base);
    for (int n = 0; n < nact; n++) {
        long i = base + n;
        B[i * HD + j] = __float2bfloat16(accB[n]);
        C[i * HD + j] = accC[n] + bb;
    }
}

__device__ __forceinline__ float bflo(unsigned u) { return __uint_as_float(u << 16); }
__device__ __forceinline__ float bfhi(unsigned u) { return __uint_as_float(u & 0xffff0000u); }

// ---- CSR gather, quad-row (4 neighbor rows per wave-load, uint2/lane) ----
// 16 lanes x 8 B cover one 128 B row; quarter q = lane>>4 owns row slot q.
// LAST=true: fuse the global mean pool: accumulate (C_row + mean_aggr) *
// invc[batch[i]] into cb via device-scope atomics.
template <bool LAST>
__global__ void k_gather(const int* __restrict__ off, const int* __restrict__ nbr,
                         const bf16* __restrict__ Bm, float* __restrict__ C,
                         const int* __restrict__ batch, const float* __restrict__ invc,
                         float* __restrict__ cb) {
    int t = blockIdx.x * 256 + threadIdx.x;
    int i = t >> 6, lane = t & 63;
    if (!LAST && i >= N_NODES) return;
    int q = lane >> 4, c2 = lane & 15;
    int wid = threadIdx.x >> 6;
    const uint2* B2 = (const uint2*)Bm;       // 16 uint2 per 64-col bf16 row
    int beg = off[i], end = off[i + 1];
    float4 a0 = make_float4(0.f, 0.f, 0.f, 0.f);
    float4 a1 = make_float4(0.f, 0.f, 0.f, 0.f);
    float4 a2 = make_float4(0.f, 0.f, 0.f, 0.f);
    float4 a3 = make_float4(0.f, 0.f, 0.f, 0.f);
    for (int base = beg; base < end; base += 64) {
        int idx = base + lane;
        int nv = (idx < end) ? nbr[idx] : 0;
        int m = min(64, end - base);
        int tt = 0;
        for (; tt + 16 <= m; tt += 16) {
            int n0 = __shfl(nv, tt + 0 + q);
            int n1 = __shfl(nv, tt + 4 + q);
            int n2 = __shfl(nv, tt + 8 + q);
            int n3 = __shfl(nv, tt + 12 + q);
            uint2 u0 = B2[(long)n0 * 16 + c2];
            uint2 u1 = B2[(long)n1 * 16 + c2];
            uint2 u2 = B2[(long)n2 * 16 + c2];
            uint2 u3 = B2[(long)n3 * 16 + c2];
            a0.x += bflo(u0.x); a0.y += bfhi(u0.x); a0.z += bflo(u0.y); a0.w += bfhi(u0.y);
            a1.x += bflo(u1.x); a1.y += bfhi(u1.x); a1.z += bflo(u1.y); a1.w += bfhi(u1.y);
            a2.x += bflo(u2.x); a2.y += bfhi(u2.x); a2.z += bflo(u2.y); a2.w += bfhi(u2.y);
            a3.x += bflo(u3.x); a3.y += bfhi(u3.x); a3.z += bflo(u3.y); a3.w += bfhi(u3.y);
        }
        for (; tt < m; tt += 4) {
            int n0 = __shfl(nv, tt + q);
            if (tt + q < m) {
                uint2 u0 = B2[(long)n0 * 16 + c2];
                a0.x += bflo(u0.x); a0.y += bfhi(u0.x);
                a0.z += bflo(u0.y); a0.w += bfhi(u0.y);
            }
        }
    }
    float4 s;
    s.x = (a0.x + a1.x) + (a2.x + a3.x);
    s.y = (a0.y + a1.y) + (a2.y + a3.y);
    s.z = (a0.z + a1.z) + (a2.z + a3.z);
    s.w = (a0.w + a1.w) + (a2.w + a3.w);
    s.x += __shfl_xor(s.x, 16); s.x += __shfl_xor(s.x, 32);
    s.y += __shfl_xor(s.y, 16); s.y += __shfl_xor(s.y, 32);
    s.z += __shfl_xor(s.z, 16); s.z += __shfl_xor(s.z, 32);
    s.w += __shfl_xor(s.w, 16); s.w += __shfl_xor(s.w, 32);
    if (!LAST) {
        if (lane < 16) {
            int deg = end - beg;
            float inv = 1.0f / (float)max(deg, 1);
            float4* Cp = (float4*)(C + (long)i * HD + 4 * lane);
            float4 cur = *Cp;
            cur.x += s.x * inv;
            cur.y += s.y * inv;
            cur.z += s.z * inv;
            cur.w += s.w * inv;
            *Cp = cur;
        }
    } else {
        // fused global-mean-pool: block covers 4 consecutive nodes (sorted batch
        // -> usually same graph); cross-wave reduce in LDS, then 64 atomics.
        __shared__ float red[4][64];
        __shared__ int gid[4];
        if (lane < 16) {
            int deg = end - beg;
            float inv = 1.0f / (float)max(deg, 1);
            const float4 cur = *(const float4*)(C + (long)i * HD + 4 * lane);
            red[wid][4 * lane + 0] = cur.x + s.x * inv;
            red[wid][4 * lane + 1] = cur.y + s.y * inv;
            red[wid][4 * lane + 2] = cur.z + s.z * inv;
            red[wid][4 * lane + 3] = cur.w + s.w * inv;
        }
        if (lane == 0) gid[wid] = batch[i];
        __syncthreads();
        if (wid == 0) {
            int g0 = gid[0], g1 = gid[1], g2 = gid[2], g3 = gid[3];
            float v0 = red[0][lane], v1 = red[1][lane];
            float v2 = red[2][lane], v3 = red[3][lane];
            if (g0 == g3) {   // sorted batch: g0==g3 implies all equal
                atomicAdd(&cb[g0 * HD + lane],
                          ((v0 + v1) + (v2 + v3)) * invc[g0]);
            } else {
                atomicAdd(&cb[g0 * HD + lane], v0 * invc[g0]);
                atomicAdd(&cb[g1 * HD + lane], v1 * invc[g1]);
                atomicAdd(&cb[g2 * HD + lane], v2 * invc[g2]);
                atomicAdd(&cb[g3 * HD + lane], v3 * invc[g3]);
            }
        }
    }
}

// ---------------- fused head, row-partitioned, LDS-staged weights ----------
// Block r owns graphs 4r..4r+3 end-to-end; intermediates stay in LDS.
// All weight matrices are staged into LDS via deep independent float4 bursts;
// lin2/lin3 staging is issued BEFORE the grid barrier so HBM latency hides
// under the barrier wait. Only BN column-statistics cross blocks.
__device__ __forceinline__ void gbar(int* bar, int round) {
    __syncthreads();
    if (threadIdx.x == 0) {
        __hip_atomic_fetch_add(bar, 1, __ATOMIC_ACQ_REL, __HIP_MEMORY_SCOPE_AGENT);
        int target = round * NB_HEAD;
        while (__hip_atomic_load(bar, __ATOMIC_ACQUIRE, __HIP_MEMORY_SCOPE_AGENT) < target) {}
    }
    __syncthreads();
}

__device__ __forceinline__ float ag_load(const float* p) {
    return __hip_atomic_load(p, __ATOMIC_RELAXED, __HIP_MEMORY_SCOPE_AGENT);
}

// copy NF floats (NF % 1024 == 0) global->LDS as float4, fully unrolled
template <int NF>
__device__ __forceinline__ void stage4(float* __restrict__ s, const float* __restrict__ g) {
    const float4* g4 = (const float4*)g;
    float4* s4 = (float4*)s;
    #pragma unroll
    for (int i = 0; i < NF / 1024; i++)
        s4[i * 256 + threadIdx.x] = g4[i * 256 + threadIdx.x];
}

__global__ __launch_bounds__(256) void k_head(
        int* bar, float* __restrict__ gstat,
        const float* __restrict__ l1w, const float* __restrict__ l1b,
        const float* __restrict__ g1, const float* __restrict__ be1,
        const float* __restrict__ l2w, const float* __restrict__ l2b,
        const float* __restrict__ g2, const float* __restrict__ be2,
        const float* __restrict__ l3w, const float* __restrict__ l3b,
        const float* __restrict__ g3, const float* __restrict__ be3,
        const float* __restrict__ w4, const float* __restrict__ b4,
        const float* __restrict__ cb, float* __restrict__ out) {
    __shared__ float WB[32768];    // 128 KB weight staging buffer
    __shared__ float A1[4][64];    // cb rows (lin1 input)
    __shared__ float A2[4][256];   // lin1 output
    __shared__ float A3[4][128];   // lin2 output
    __shared__ float M3[4][64];    // lin3 output
    __shared__ float W4[640];      // lin4 weights
    float* gs1 = gstat;            // [256] lin1 col sums
    float* gq1 = gstat + 256;      // [256]
    float* gs2 = gstat + 512;      // [128]
    float* gq2 = gstat + 640;      // [128]
    float* gs3 = gstat + 768;      // [64]
    float* gq3 = gstat + 832;      // [64]
    int t = threadIdx.x;
    int r0 = blockIdx.x * 4;       // first graph row owned by this block

    // phase 0: stage lin1_w (64 KB) into WB[16384..32768), w4, cb rows
    {
        int r = t >> 6, lane = t & 63;
        A1[r][lane] = cb[(r0 + r) * HD + lane];
    }
    if (t < 160) ((float4*)W4)[t] = ((const float4*)w4)[t];
    stage4<16384>(WB + 16384, l1w);
    __syncthreads();

    // ---- lin1: K=64 -> N=256; thread t owns column t for all 4 rows ----
    float v1[4];
    {
        float bj = l1b[t];
        v1[0] = bj; v1[1] = bj; v1[2] = bj; v1[3] = bj;
        const float* Wp = WB + 16384;
        #pragma unroll 16
        for (int k = 0; k < 64; k++) {
            float w = Wp[k * 256 + t];
            v1[0] = fmaf(A1[0][k], w, v1[0]);
            v1[1] = fmaf(A1[1][k], w, v1[1]);
            v1[2] = fmaf(A1[2][k], w, v1[2]);
            v1[3] = fmaf(A1[3][k], w, v1[3]);
        }
        float s = (v1[0] + v1[1]) + (v1[2] + v1[3]);
        float q = (v1[0] * v1[0] + v1[1] * v1[1]) + (v1[2] * v1[2] + v1[3] * v1[3]);
        atomicAdd(&gs1[t], s);
        atomicAdd(&gq1[t], q);
    }
    __syncthreads();                 // all waves done reading WB hi
    stage4<32768>(WB, l2w);          // full lin2_w; latency hides under barrier
    gbar(bar, 1);
    {
        float S = ag_load(&gs1[t]), Q = ag_load(&gq1[t]);
        float mean = S * (1.0f / NUM_GRAPHS);
        float var = Q * (1.0f / NUM_GRAPHS) - mean * mean;
        float sc = rsqrtf(fmaxf(var, 0.f) + EPS) * g1[t];
        float sh = be1[t];
        #pragma unroll
        for (int r = 0; r < 4; r++)
            A2[r][t] = tanhf((v1[r] - mean) * sc + sh);
    }
    __syncthreads();                 // A2 ready (WB ready via gbar's barrier)

    // ---- lin2: K=256 -> N=128; thread = (col j2, rowpair rq2) ----
    float v2[2];
    int j2 = t & 127, rq2 = t >> 7;
    {
        float bj = l2b[j2];
        v2[0] = bj; v2[1] = bj;
        const float* a0 = A2[2 * rq2 + 0];
        const float* a1 = A2[2 * rq2 + 1];
        #pragma unroll 16
        for (int k = 0; k < 256; k++) {
            float w = WB[k * 128 + j2];
            v2[0] = fmaf(a0[k], w, v2[0]);
            v2[1] = fmaf(a1[k], w, v2[1]);
        }
        atomicAdd(&gs2[j2], v2[0] + v2[1]);
        atomicAdd(&gq2[j2], v2[0] * v2[0] + v2[1] * v2[1]);
    }
    __syncthreads();                 // all waves done reading WB
    stage4<8192>(WB, l3w);           // lin3_w; latency hides under barrier
    gbar(bar, 2);
    {
        float S = ag_load(&gs2[j2]), Q = ag_load(&gq2[j2]);
        float mean = S * (1.0f / NUM_GRAPHS);
        float var = Q * (1.0f / NUM_GRAPHS) - mean * mean;
        float sc = rsqrtf(fmaxf(var, 0.f) + EPS) * g2[j2];
        float sh = be2[j2];
        A3[2 * rq2 + 0][j2] = tanhf((v2[0] - mean) * sc + sh);
        A3[2 * rq2 + 1][j2] = tanhf((v2[1] - mean) * sc + sh);
    }
    __syncthreads();                 // A3 ready (WB ready via gbar's barrier)

    // ---- lin3: K=128 -> N=64; thread = (col j3, row rq3) ----
    float v3;
    int j3 = t & 63, rq3 = t >> 6;
    {
        float bj = l3b[j3];
        v3 = bj;
        const float* a = A3[rq3];
        #pragma unroll 16
        for (int k = 0; k < 128; k++) {
            float w = WB[k * 64 + j3];
            v3 = fmaf(a[k], w, v3);
        }
        atomicAdd(&gs3[j3], v3);
        atomicAdd(&gq3[j3], v3 * v3);
    }
    gbar(bar, 3);
    {
        float S = ag_load(&gs3[j3]), Q = ag_load(&gq3[j3]);
        float mean = S * (1.0f / NUM_GRAPHS);
        float var = Q * (1.0f / NUM_GRAPHS) - mean * mean;
        float sc = rsqrtf(fmaxf(var, 0.f) + EPS) * g3[j3];
        float sh = be3[j3];
        M3[rq3][j3] = tanhf((v3 - mean) * sc + sh);
    }
    __syncthreads();

    // ---- lin4: 4 rows x 10 outputs, all LDS-local ----
    if (t < 40) {
        int q = t / 10, jf = t % 10;
        const float* rp = M3[q];
        float s = b4[jf];
        #pragma unroll
        for (int k = 0; k < 64; k++) s = fmaf(rp[k], W4[k * 10 + jf], s);
        out[(r0 + q) * 10 + jf] = s;
    }
}

extern "C" void kernel_launch(void* const* d_in, const int* in_sizes, int n_in,
                              void* d_out, int out_size, void* d_ws, size_t ws_size,
                              hipStream_t stream) {
    const float* x     = (const float*)d_in[0];
    const int*   ei    = (const int*) d_in[1];
    const int*   batch = (const int*) d_in[2];
    const float *W1l = (const float*)d_in[3],  *b1l = (const float*)d_in[4],  *W1r = (const float*)d_in[5];
    const float *W2l = (const float*)d_in[6],  *b2l = (const float*)d_in[7],  *W2r = (const float*)d_in[8];
    const float *W3l = (const float*)d_in[9],  *b3l = (const float*)d_in[10], *W3r = (const float*)d_in[11];
    const float *lin1_w = (const float*)d_in[12], *lin1_b = (const float*)d_in[13];
    const float *g1 = (const float*)d_in[14], *be1 = (const float*)d_in[15];
    const float *lin2_w = (const float*)d_in[16], *lin2_b = (const float*)d_in[17];
    const float *g2 = (const float*)d_in[18], *be2 = (const float*)d_in[19];
    const float *lin3_w = (const float*)d_in[20], *lin3_b = (const float*)d_in[21];
    const float *g3 = (const float*)d_in[22], *be3 = (const float*)d_in[23];
    const float *lin4_w = (const float*)d_in[24], *lin4_b = (const float*)d_in[25];

    const int* srcp = ei;
    const int* dstp = ei + N_EDGES;

    // ---- workspace layout ----
    const long NF = (long)N_NODES * HD;              // 3,200,000
    char* wsb  = (char*)d_ws;
    int*  cnti = (int*)wsb;                          // 50,048
    int*  bar  = cnti + 50048;                       // 8
    float* gstat = (float*)(bar + 8);                // 896 (zeroed with cnti)
    int*  pos  = (int*)(gstat + 896);                // 800,000
    int*  off  = pos  + 800000;                      // 50,056
    int*  nbr  = off  + 50056;                       // 800,000
    int*  bsum = nbr  + 800000;                      // 256
    int*  gb   = bsum + 256;                         // 264 (257 used)
    float* invc = (float*)(gb + 264);                // 256
    bf16* B    = (bf16*)(invc + 256);                // 3,200,000 bf16
    float* H1  = (float*)(B + NF);                   // 3,200,000
    float* H2  = H1  + NF;                           // 3,200,000
    float* cb  = H2  + NF;                           // 16,384
    float* endp= cb  + NUM_GRAPHS * HD;

    const size_t NEED = (size_t)((char*)endp - wsb);
    if (ws_size < NEED) {
        k_diag<<<(out_size + 255) / 256, 256, 0, stream>>>((float*)d_out, out_size,
                                                           (float)(ws_size >> 20));
        return;
    }

    const int TB = 256;
    const int gNE = (N_EDGES + TB - 1) / TB;
    const int gNF = (int)((NF + TB - 1) / TB);        // 12500 (= exactly 50000 nodes)
    const int gXB = (N_NODES + 63) / 64;              // 782

    hipMemsetAsync(cnti, 0, (50048 + 8 + 896) * sizeof(int), stream);
    hipMemsetAsync(cb, 0, NUM_GRAPHS * HD * sizeof(float), stream);

    // ---- CSR build (+ graph bounds) ----
    k_count<<<gNE, TB, 0, stream>>>(dstp, batch, cnti, pos, gb);
    k_scan1<<<SCAN_NB, TB, 0, stream>>>(cnti, off, bsum);
    k_scan3<<<SCAN_NB, TB, 0, stream>>>(off, bsum, gb, invc);
    k_fill<<<gNE, TB, 0, stream>>>(srcp, dstp, off, pos, nbr);

    // ---- SAGE layers (bf16 messages, quad-row gather) ----
    k_xform3<IN_DIM><<<gXB, TB, 0, stream>>>(x, W1l, W1r, b1l, B, H1);
    k_gather<false><<<gNF, TB, 0, stream>>>(off, nbr, B, H1, batch, invc, cb);
    k_xform3<HD><<<gXB, TB, 0, stream>>>(H1, W2l, W2r, b2l, B, H2);
    k_gather<false><<<gNF, TB, 0, stream>>>(off, nbr, B, H2, batch, invc, cb);
    k_xform3<HD><<<gXB, TB, 0, stream>>>(H2, W3l, W3r, b3l, B, H1);
    // last gather: fused global-mean-pool into cb (H1 never written back)
    k_gather<true><<<gNF, TB, 0, stream>>>(off, nbr, B, H1, batch, invc, cb);

    // ---- fused head: row-partitioned, LDS-staged weights ----
    k_head<<<NB_HEAD, TB, 0, stream>>>(bar, gstat,
                                       lin1_w, lin1_b, g1, be1,
                                       lin2_w, lin2_b, g2, be2,
                                       lin3_w, lin3_b, g3, be3,
                                       lin4_w, lin4_b,
                                       cb, (float*)d_out);
}